// Round 10
// baseline (854.503 us; speedup 1.0000x reference)
//
#include <hip/hip_runtime.h>
#include <hip/hip_bf16.h>

// Problem constants (from reference)
#define BT 4096
#define HD 2048
#define VD 32000
#define IGNORE_IDX (-100)

// ---- 256x256 8-phase GEMM geometry (fast path) ----
#define BM2 256
#define BN2 256
#define BK2 64
#define NRB2 (BT / BM2)  // 16
#define NCB2 (VD / BN2)  // 125
#define NKT (HD / BK2)   // 32

// ---- 128x128 fallback geometry (fp32 path) ----
#define BM 128
#define BN 128
#define BKT 32
#define NRB (BT / BM)  // 32
#define NCB (VD / BN)  // 250

using short8 = __attribute__((ext_vector_type(8))) short;
using f32x4 = __attribute__((ext_vector_type(4))) float;

__device__ __forceinline__ unsigned short f2bf(float f) {
  unsigned u = __float_as_uint(f);
  u = (u + 0x7fffu + ((u >> 16) & 1u)) >> 16;
  return (unsigned short)u;
}

// async global->LDS, 16B/lane; LDS dest = wave-uniform base + lane*16.
// offset param MUST stay 0 (R3/R4 NaN root cause) -- all offsets folded
// into the global pointer.
#define GL(SRC, DST)                                         \
  __builtin_amdgcn_global_load_lds(                          \
      (const __attribute__((address_space(1))) void*)(SRC),  \
      (__attribute__((address_space(3))) void*)(DST), 16, 0, 0)

// stage one half-tile (128 rows x 64 K bf16 = 16KB): 2 issues per thread.
#define STG2(GSRC, KOFF, DBASE, SLOT)                 \
  GL((GSRC) + (KOFF), (DBASE) + (SLOT)*8192);         \
  GL((GSRC) + (KOFF) + 32, (DBASE) + (SLOT)*8192 + 512)

// ---------------------------------------------------------------------------
// Detect whether target buffer is int64 or int32 (reads 16KB, safe either way)
// ---------------------------------------------------------------------------
__global__ void detect_tgt_kernel(const long long* __restrict__ t64,
                                  int* __restrict__ badcnt) {
  int i = blockIdx.x * blockDim.x + threadIdx.x;  // 2048 threads
  long long v = t64[i];
  bool valid = (v == (long long)IGNORE_IDX) || (v >= 0 && v < (long long)VD);
  if (!valid) atomicAdd(badcnt, 1);
}

// ---------------------------------------------------------------------------
// fp32 -> bf16 bulk convert
// ---------------------------------------------------------------------------
__global__ void cvt_bf16_kernel(const float* __restrict__ in,
                                unsigned short* __restrict__ out, int n8) {
  int idx = blockIdx.x * blockDim.x + threadIdx.x;
  int stride = gridDim.x * blockDim.x;
  for (int i = idx; i < n8; i += stride) {
    float4 a = ((const float4*)in)[(size_t)2 * i];
    float4 b = ((const float4*)in)[(size_t)2 * i + 1];
    short8 o;
    o[0] = (short)f2bf(a.x);
    o[1] = (short)f2bf(a.y);
    o[2] = (short)f2bf(a.z);
    o[3] = (short)f2bf(a.w);
    o[4] = (short)f2bf(b.x);
    o[5] = (short)f2bf(b.y);
    o[6] = (short)f2bf(b.z);
    o[7] = (short)f2bf(b.w);
    ((short8*)out)[i] = o;
  }
}

// ---------------------------------------------------------------------------
// FAST PATH: 256x256 bf16 GEMM, BK=64, 128KB LDS double-buffer, 8-phase
// schedule with ONE-PHASE-EARLY ds_reads (counted-wait overlap) + counted
// vmcnt, fused with per-(rb,cb) sum(exp) and picked-target-logit.
//
// LDS: A/B = 4 slots x 8192 hw each (slot = buf*2 + half), FRAGMENT-ORDER
// (staging LDS-linear, per-lane global source permuted; ds_read lane-linear:
// zero bank conflicts).
//
// Per tile tau (4 phases), segments sigma_i before phase i's open barrier:
//   s1: RD bHi(tau)                      P1: acc[0..3][0..1] += aLo x bLo
//   s2: RD aHi(tau)                      P2: acc[0..3][2..3] += aLo x bHi
//   s3: STG B0,B1(tau+2); vmcnt(4)       P3: acc[4..7][2..3] += aHi x bHi
//   s4: STG A0,A1(tau+2); RD aLo,bLo'(tau+1)  P4: acc[4..7][0..1] += aHi x bLo
// Every read batch has >=1 full MFMA phase to drain before its consuming
// phase (compiler inserts minimal counted lgkm waits). vmcnt(4) sits before
// P3's OPEN barrier so all waves pass the gate before any wave's s4 reads
// of tile tau+1 (cross-wave safety). bLo is register-double-buffered (E/O);
// aLo/aHi/bHi lifetimes verified single-buffer safe. Slot WAR: B-slots
// staged at s3 (last read bHi retires at P2-open); A-slots at s4 (aHi
// retires P3-open). Ledger: steady outstanding 12 at s3 gate; vmcnt(4)
// drains exactly tile tau+1's 8 issues.
// ---------------------------------------------------------------------------
__global__ __launch_bounds__(512) void gemm_lse_8ph_kernel(
    const unsigned short* __restrict__ xbf,
    const unsigned short* __restrict__ wbf, const void* __restrict__ tgt,
    const int* __restrict__ badcnt, float* __restrict__ partialS,
    float* __restrict__ picked) {
  __shared__ unsigned short smem[65536];  // 128 KB
  unsigned short* ldsA = smem;            // 4 slots * 8192 hw
  unsigned short* ldsB = smem + 32768;

  const int t = threadIdx.x;

  // zero-init LDS (defensive: residual bug -> finite-wrong, never NaN)
  {
    uint4 z = make_uint4(0u, 0u, 0u, 0u);
#pragma unroll
    for (int i = 0; i < 16; i++) ((uint4*)smem)[t + i * 512] = z;
  }
  __syncthreads();

  // T1: bijective XCD swizzle (2000 % 8 == 0), rowblock-fast
  const int bid = blockIdx.x;
  const int cpx = (NRB2 * NCB2) >> 3;  // 250
  const int swz = (bid & 7) * cpx + (bid >> 3);
  const int rb = swz % NRB2;
  const int cb = swz / NRB2;
  const int row0 = rb * BM2;
  const int col0 = cb * BN2;

  const int lane = t & 63;
  const int w = t >> 6;    // 0..7
  const int wm = w >> 2;   // 0..1  (A half)
  const int wn = w & 3;    // 0..3
  const int bh = wn >> 1;  // B half
  const int bn4 = wn & 1;  // 64-col subrange within B half

  const int fr = lane & 15;
  const int kq = lane >> 4;  // 0..3

  // read-side LDS bases (fragment-order): lane-linear, conflict-free
  const unsigned short* pA0 = ldsA + (0 * 2 + wm) * 8192 + lane * 8;
  const unsigned short* pA1 = ldsA + (1 * 2 + wm) * 8192 + lane * 8;
  const unsigned short* pB0 =
      ldsB + (0 * 2 + bh) * 8192 + bn4 * 4096 + lane * 8;
  const unsigned short* pB1 =
      ldsB + (1 * 2 + bh) * 8192 + bn4 * 4096 + lane * 8;

  // staging: wave w stages 16-row block i=w of each half-tile; lane
  // l = kq*16+fr sources global (row = w*16 + (l&15), k = (l>>4)*8) and
  // lands at LDS linear l*16B -> fragment-order layout.
  const int srow = lane & 15;
  const int scol = (lane >> 4) * 8;
  const unsigned short* gA0 =
      xbf + (size_t)(row0 + 0 + w * 16 + srow) * HD + scol;
  const unsigned short* gA1 =
      xbf + (size_t)(row0 + 128 + w * 16 + srow) * HD + scol;
  const unsigned short* gB0 =
      wbf + (size_t)(col0 + 0 + w * 16 + srow) * HD + scol;
  const unsigned short* gB1 =
      wbf + (size_t)(col0 + 128 + w * 16 + srow) * HD + scol;

  unsigned short* dA = ldsA + w * 1024;  // wave's 2KB region within a slot
  unsigned short* dB = ldsB + w * 1024;

  f32x4 acc[8][4];
#pragma unroll
  for (int i = 0; i < 8; i++)
#pragma unroll
    for (int n = 0; n < 4; n++)
#pragma unroll
      for (int q = 0; q < 4; q++) acc[i][n][q] = 0.f;

  short8 aLo[4][2], aHi[4][2], bLoE[2][2], bLoO[2][2], bHi[2][2];

#define RDALO(P, D)                                    \
  _Pragma("unroll") for (int i = 0; i < 4; i++)        \
  _Pragma("unroll") for (int k2 = 0; k2 < 2; k2++)     \
      D[i][k2] = *(const short8*)((P) + i * 1024 + k2 * 512);

#define RDAHI(P, D)                                    \
  _Pragma("unroll") for (int i = 0; i < 4; i++)        \
  _Pragma("unroll") for (int k2 = 0; k2 < 2; k2++)     \
      D[i][k2] = *(const short8*)((P) + (i + 4) * 1024 + k2 * 512);

#define RDBLO(P, D)                                    \
  _Pragma("unroll") for (int n = 0; n < 2; n++)        \
  _Pragma("unroll") for (int k2 = 0; k2 < 2; k2++)     \
      D[n][k2] = *(const short8*)((P) + n * 1024 + k2 * 512);

#define RDBHI(P, D)                                    \
  _Pragma("unroll") for (int n = 0; n < 2; n++)        \
  _Pragma("unroll") for (int k2 = 0; k2 < 2; k2++)     \
      D[n][k2] = *(const short8*)((P) + (n + 2) * 1024 + k2 * 512);

#define PH(I0, N0, AF, BF)                                                    \
  __builtin_amdgcn_sched_barrier(0);                                          \
  __builtin_amdgcn_s_barrier();                                               \
  __builtin_amdgcn_sched_barrier(0);                                          \
  __builtin_amdgcn_s_setprio(1);                                              \
  _Pragma("unroll") for (int k2 = 0; k2 < 2; k2++)                            \
  _Pragma("unroll") for (int i = 0; i < 4; i++)                               \
  _Pragma("unroll") for (int n = 0; n < 2; n++)                               \
      acc[(I0) + i][(N0) + n] = __builtin_amdgcn_mfma_f32_16x16x32_bf16(      \
          AF[i][k2], BF[n][k2], acc[(I0) + i][(N0) + n], 0, 0, 0);            \
  __builtin_amdgcn_s_setprio(0);                                              \
  __builtin_amdgcn_sched_barrier(0);                                          \
  __builtin_amdgcn_s_barrier();                                               \
  __builtin_amdgcn_sched_barrier(0);

  // ---- prologue: stage tiles 0 and 1 fully (16 issues); drain tile0;
  //      barrier (cross-wave); read aLo,bLoE(0) ----
  STG2(gB0, 0, dB, 0);   // B0(0)
  STG2(gB1, 0, dB, 1);   // B1(0)
  STG2(gA0, 0, dA, 0);   // A0(0)
  STG2(gA1, 0, dA, 1);   // A1(0)
  STG2(gB0, 64, dB, 2);  // B0(1)
  STG2(gB1, 64, dB, 3);  // B1(1)
  STG2(gA0, 64, dA, 2);  // A0(1)
  STG2(gA1, 64, dA, 3);  // A1(1)
  asm volatile("s_waitcnt vmcnt(8)" ::: "memory");  // tile0 landed
  __builtin_amdgcn_s_barrier();                     // all waves past gate
  RDALO(pA0, aLo);
  RDBLO(pB0, bLoE);

  // ---- main loop: 2 tiles/iter; stages tiles kt+2 (s3/s4), kt+3 (s7/s8) --
  for (int kt = 0; kt + 3 < NKT; kt += 2) {
    // tile kt (buf0)
    RDBHI(pB0, bHi);            // s1
    PH(0, 0, aLo, bLoE);        // P1
    RDAHI(pA0, aHi);            // s2
    PH(0, 2, aLo, bHi);         // P2
    STG2(gB0, 128, dB, 0);      // s3: B0(kt+2)
    STG2(gB1, 128, dB, 1);      //     B1(kt+2)
    asm volatile("s_waitcnt vmcnt(4)" ::: "memory");  // tile kt+1 landed
    PH(4, 2, aHi, bHi);         // P3
    STG2(gA0, 128, dA, 0);      // s4: A0(kt+2)
    STG2(gA1, 128, dA, 1);      //     A1(kt+2)
    RDALO(pA1, aLo);            //     reads of tile kt+1 (safe: gate at s3)
    RDBLO(pB1, bLoO);
    PH(4, 0, aHi, bLoE);        // P4
    // tile kt+1 (buf1)
    RDBHI(pB1, bHi);            // s5
    PH(0, 0, aLo, bLoO);        // P5
    RDAHI(pA1, aHi);            // s6
    PH(0, 2, aLo, bHi);         // P6
    STG2(gB0, 192, dB, 2);      // s7: B0(kt+3)
    STG2(gB1, 192, dB, 3);      //     B1(kt+3)
    asm volatile("s_waitcnt vmcnt(4)" ::: "memory");  // tile kt+2 landed
    PH(4, 2, aHi, bHi);         // P7
    STG2(gA0, 192, dA, 2);      // s8: A0(kt+3)
    STG2(gA1, 192, dA, 3);      //     A1(kt+3)
    RDALO(pA0, aLo);            //     reads of tile kt+2
    RDBLO(pB0, bLoE);
    PH(4, 0, aHi, bLoO);        // P8
    gA0 += 128;  // advance 2 K-tiles
    gA1 += 128;
    gB0 += 128;
    gB1 += 128;
  }

  // ---- tail: tiles NKT-2 (buf0), NKT-1 (buf1); fully staged already ----
  {
    RDBHI(pB0, bHi);
    PH(0, 0, aLo, bLoE);
    RDAHI(pA0, aHi);
    PH(0, 2, aLo, bHi);
    asm volatile("s_waitcnt vmcnt(0)" ::: "memory");  // tile NKT-1 landed
    PH(4, 2, aHi, bHi);
    RDALO(pA1, aLo);
    RDBLO(pB1, bLoO);
    PH(4, 0, aHi, bLoE);
    RDBHI(pB1, bHi);
    PH(0, 0, aLo, bLoO);
    RDAHI(pA1, aHi);
    PH(0, 2, aLo, bHi);
    PH(4, 2, aHi, bHi);
    PH(4, 0, aHi, bLoO);
  }

  // ---- epilogue: per-row sum(exp) over this block's 256 cols ----
  // C/D layout: col = col0 + wn*64 + n*16 + fr ;
  //             row = row0 + wm*128 + i*16 + kq*4 + q
  __syncthreads();
  float* red = (float*)smem;  // [256 rows][4 wn] floats = 4KB
#pragma unroll
  for (int i = 0; i < 8; i++) {
#pragma unroll
    for (int q = 0; q < 4; q++) {
      float s = 0.f;
#pragma unroll
      for (int n = 0; n < 4; n++) s += __expf(acc[i][n][q]);
#pragma unroll
      for (int m = 1; m < 16; m <<= 1) s += __shfl_xor(s, m, 64);
      if (fr == 0) red[(wm * 128 + i * 16 + kq * 4 + q) * 4 + wn] = s;
    }
  }
  __syncthreads();
  if (t < 256) {
    float S = red[t * 4 + 0] + red[t * 4 + 1] + red[t * 4 + 2] + red[t * 4 + 3];
    partialS[(size_t)cb * BT + row0 + t] = S;
  }

  // ---- picked target logit (single writer per row across the grid) ----
  const bool is64 = (*badcnt == 0);
#pragma unroll
  for (int i = 0; i < 8; i++) {
#pragma unroll
    for (int q = 0; q < 4; q++) {
      int grow = row0 + wm * 128 + i * 16 + kq * 4 + q;
      long long tv = is64 ? ((const long long*)tgt)[grow]
                          : (long long)((const int*)tgt)[grow];
#pragma unroll
      for (int n = 0; n < 4; n++) {
        int gcol = col0 + wn * 64 + n * 16 + fr;
        if (tv == (long long)gcol) picked[grow] = acc[i][n][q];
      }
    }
  }
#undef RDALO
#undef RDAHI
#undef RDBLO
#undef RDBHI
#undef PH
}

// ---------------------------------------------------------------------------
// FALLBACK PATH (ws too small): fp32 inputs with on-the-fly cvt
// ---------------------------------------------------------------------------
__global__ __launch_bounds__(256) void gemm_lse_kernel(
    const float* __restrict__ x, const float* __restrict__ w,
    const void* __restrict__ tgt, const int* __restrict__ badcnt,
    float* __restrict__ partialS, float* __restrict__ picked) {
  __shared__ unsigned short As[BM][BKT];
  __shared__ unsigned short Bs[BN][BKT];

  const int bid = blockIdx.x;
  const int rb = bid % NRB;
  const int cb = bid / NRB;
  const int row0 = rb * BM;
  const int col0 = cb * BN;
  const int t = threadIdx.x;
  const int lane = t & 63;
  const int wave = t >> 6;
  const int wr = wave >> 1;
  const int wc = wave & 1;

  const int srow = t >> 3;
  const int scol = (t & 7) * 4;

  const float* xA = x + (size_t)row0 * HD;
  const float* wB = w + (size_t)col0 * HD;

  f32x4 acc[4][4];
#pragma unroll
  for (int i = 0; i < 4; i++)
#pragma unroll
    for (int j = 0; j < 4; j++)
#pragma unroll
      for (int q = 0; q < 4; q++) acc[i][j][q] = 0.f;

  float4 ra[4], rbv[4];

#define STAGE_LOAD(k0)                                                        \
  {                                                                           \
    _Pragma("unroll") for (int j = 0; j < 4; j++) {                           \
      ra[j] = *(const float4*)(xA + (size_t)(srow + j * 32) * HD + (k0) + scol); \
      rbv[j] = *(const float4*)(wB + (size_t)(srow + j * 32) * HD + (k0) + scol); \
    }                                                                         \
  }
#define STAGE_WRITE()                                                         \
  {                                                                           \
    _Pragma("unroll") for (int j = 0; j < 4; j++) {                           \
      ushort4 pa = make_ushort4(f2bf(ra[j].x), f2bf(ra[j].y), f2bf(ra[j].z),  \
                                f2bf(ra[j].w));                               \
      ushort4 pb = make_ushort4(f2bf(rbv[j].x), f2bf(rbv[j].y),               \
                                f2bf(rbv[j].z), f2bf(rbv[j].w));              \
      *(ushort4*)&As[srow + j * 32][scol] = pa;                               \
      *(ushort4*)&Bs[srow + j * 32][scol] = pb;                               \
    }                                                                         \
  }

  const int ks = (lane >> 4) * 8;
  const int fr = lane & 15;

  STAGE_LOAD(0);
  STAGE_WRITE();
  __syncthreads();

  for (int k0 = 0; k0 < HD; k0 += BKT) {
    const bool notlast = (k0 + BKT < HD);
    if (notlast) STAGE_LOAD(k0 + BKT);

    short8 af[4], bfv[4];
#pragma unroll
    for (int i = 0; i < 4; i++) {
      af[i] = *(const short8*)&As[wr * 64 + i * 16 + fr][ks];
      bfv[i] = *(const short8*)&Bs[wc * 64 + i * 16 + fr][ks];
    }
#pragma unroll
    for (int i = 0; i < 4; i++)
#pragma unroll
      for (int j = 0; j < 4; j++)
        acc[i][j] = __builtin_amdgcn_mfma_f32_16x16x32_bf16(af[i], bfv[j],
                                                            acc[i][j], 0, 0, 0);

    __syncthreads();
    if (notlast) STAGE_WRITE();
    __syncthreads();
  }
#undef STAGE_LOAD
#undef STAGE_WRITE

  float rsum[16];
#pragma unroll
  for (int mi = 0; mi < 4; mi++) {
#pragma unroll
    for (int r = 0; r < 4; r++) {
      float s = 0.f;
#pragma unroll
      for (int nj = 0; nj < 4; nj++) s += __expf(acc[mi][nj][r]);
      rsum[mi * 4 + r] = s;
    }
  }
#pragma unroll
  for (int m = 1; m < 16; m <<= 1) {
#pragma unroll
    for (int q = 0; q < 16; q++) rsum[q] += __shfl_xor(rsum[q], m, 64);
  }

  __syncthreads();
  float* red = (float*)&As[0][0];
  if (fr == 0) {
#pragma unroll
    for (int mi = 0; mi < 4; mi++)
#pragma unroll
      for (int r = 0; r < 4; r++)
        red[wave * 64 + mi * 16 + (lane >> 4) * 4 + r] = rsum[mi * 4 + r];
  }
  __syncthreads();

  if (t < BM) {
    int rl = t;
    int wrow = rl >> 6;
    float S = red[(wrow * 2 + 0) * 64 + (rl & 63)] +
              red[(wrow * 2 + 1) * 64 + (rl & 63)];
    partialS[(size_t)cb * BT + row0 + rl] = S;
  }

  const bool is64 = (*badcnt == 0);
#pragma unroll
  for (int mi = 0; mi < 4; mi++) {
#pragma unroll
    for (int r = 0; r < 4; r++) {
      int grow = row0 + wr * 64 + mi * 16 + ((lane >> 4) << 2) + r;
      long long tv = is64 ? ((const long long*)tgt)[grow]
                          : (long long)((const int*)tgt)[grow];
#pragma unroll
      for (int nj = 0; nj < 4; nj++) {
        int gcol = col0 + wc * 64 + nj * 16 + fr;
        if (tv == (long long)gcol) picked[grow] = acc[mi][nj][r];
      }
    }
  }
}

// ---------------------------------------------------------------------------
// Per-row: S = sum of ncb partials; nll = log(S) - picked.
// ---------------------------------------------------------------------------
__global__ void reduce_rows_kernel(const float* __restrict__ partialS,
                                   const float* __restrict__ picked,
                                   float* __restrict__ nll, int ncb) {
  int r = blockIdx.x * blockDim.x + threadIdx.x;
  if (r >= BT) return;
  float S = 0.f;
  for (int cb = 0; cb < ncb; cb++) S += partialS[(size_t)cb * BT + r];
  nll[r] = logf(fmaxf(S, 1e-37f)) - picked[r];
}

// ---------------------------------------------------------------------------
// Final: loss = sum(nll) / n_non_ignore
// ---------------------------------------------------------------------------
__global__ void reduce_final_kernel(const float* __restrict__ nll,
                                    const void* __restrict__ tgt,
                                    const int* __restrict__ badcnt,
                                    float* __restrict__ out) {
  __shared__ float ssum[256];
  __shared__ int scnt[256];
  int t = threadIdx.x;
  const bool is64 = (*badcnt == 0);
  float s = 0.f;
  int c = 0;
  for (int r = t; r < BT; r += 256) {
    s += nll[r];
    long long tv =
        is64 ? ((const long long*)tgt)[r] : (long long)((const int*)tgt)[r];
    c += (tv != (long long)IGNORE_IDX) ? 1 : 0;
  }
  ssum[t] = s;
  scnt[t] = c;
  __syncthreads();
  for (int o = 128; o > 0; o >>= 1) {
    if (t < o) {
      ssum[t] += ssum[t + o];
      scnt[t] += scnt[t + o];
    }
    __syncthreads();
  }
  if (t == 0) out[0] = ssum[0] / (float)scnt[0];
}

// ---------------------------------------------------------------------------
extern "C" void kernel_launch(void* const* d_in, const int* in_sizes, int n_in,
                              void* d_out, int out_size, void* d_ws,
                              size_t ws_size, hipStream_t stream) {
  const float* x = (const float*)d_in[0];
  const float* w = (const float*)d_in[1];
  const void* tgt = d_in[2];
  float* out = (float*)d_out;

  char* ws = (char*)d_ws;
  // ws layout:
  //   [0, offA)              : partialS (NCB*BT*4 = 4,096,000 B max)
  //   [offA, offA+16)        : badcnt flag (+pad)
  //   [offA+16, +BT*4)       : picked
  //   [.. +BT*4)             : nll
  //   [offX, +BT*HD*2)       : x as bf16
  //   [offW, +VD*HD*2)       : W as bf16
  const size_t offA = (size_t)NCB * BT * 4;
  float* partialS = (float*)ws;
  int* badcnt = (int*)(ws + offA);
  float* picked = (float*)(ws + offA + 16);
  float* nll = (float*)(ws + offA + 16 + (size_t)BT * 4);
  const size_t offX = offA + 16 + 2 * (size_t)BT * 4;
  const size_t offW = offX + (size_t)BT * HD * 2;
  const size_t need = offW + (size_t)VD * HD * 2;

  hipMemsetAsync(ws + offA, 0, 16 + (size_t)BT * 4, stream);

  detect_tgt_kernel<<<8, 256, 0, stream>>>((const long long*)tgt, badcnt);

  if (ws_size >= need) {
    unsigned short* xbf = (unsigned short*)(ws + offX);
    unsigned short* wbf = (unsigned short*)(ws + offW);
    cvt_bf16_kernel<<<2048, 256, 0, stream>>>(x, xbf, BT * HD / 8);
    cvt_bf16_kernel<<<2048, 256, 0, stream>>>(w, wbf, VD * HD / 8);
    gemm_lse_8ph_kernel<<<NRB2 * NCB2, 512, 0, stream>>>(xbf, wbf, tgt, badcnt,
                                                         partialS, picked);
    reduce_rows_kernel<<<BT / 256, 256, 0, stream>>>(partialS, picked, nll,
                                                     NCB2);
  } else {
    gemm_lse_kernel<<<NRB * NCB, 256, 0, stream>>>(x, w, tgt, badcnt, partialS,
                                                   picked);
    reduce_rows_kernel<<<BT / 256, 256, 0, stream>>>(partialS, picked, nll,
                                                     NCB);
  }

  reduce_final_kernel<<<1, 256, 0, stream>>>(nll, tgt, badcnt, out);
}

// Round 11
// 847.225 us; speedup vs baseline: 1.0086x; 1.0086x over previous
//
#include <hip/hip_runtime.h>
#include <hip/hip_bf16.h>

// Problem constants (from reference)
#define BT 4096
#define HD 2048
#define VD 32000
#define IGNORE_IDX (-100)

// ---- 256x256 8-phase GEMM geometry (fast path) ----
#define BM2 256
#define BN2 256
#define BK2 64
#define NRB2 (BT / BM2)  // 16
#define NCB2 (VD / BN2)  // 125
#define NKT (HD / BK2)   // 32

// ---- 128x128 fallback geometry (fp32 path) ----
#define BM 128
#define BN 128
#define BKT 32
#define NRB (BT / BM)  // 32
#define NCB (VD / BN)  // 250

using short8 = __attribute__((ext_vector_type(8))) short;
using f32x4 = __attribute__((ext_vector_type(4))) float;

__device__ __forceinline__ unsigned short f2bf(float f) {
  unsigned u = __float_as_uint(f);
  u = (u + 0x7fffu + ((u >> 16) & 1u)) >> 16;
  return (unsigned short)u;
}

// async global->LDS, 16B/lane; LDS dest = wave-uniform base + lane*16.
// offset param MUST stay 0 (R3/R4 NaN root cause) -- all offsets folded
// into the global pointer.
#define GL(SRC, DST)                                         \
  __builtin_amdgcn_global_load_lds(                          \
      (const __attribute__((address_space(1))) void*)(SRC),  \
      (__attribute__((address_space(3))) void*)(DST), 16, 0, 0)

// stage one half-tile (128 rows x 64 K bf16 = 16KB): 2 issues per thread.
#define STG2(GSRC, KOFF, DBASE, SLOT)                 \
  GL((GSRC) + (KOFF), (DBASE) + (SLOT)*8192);         \
  GL((GSRC) + (KOFF) + 32, (DBASE) + (SLOT)*8192 + 512)

// ---------------------------------------------------------------------------
// Detect whether target buffer is int64 or int32 (reads 16KB, safe either way)
// ---------------------------------------------------------------------------
__global__ void detect_tgt_kernel(const long long* __restrict__ t64,
                                  int* __restrict__ badcnt) {
  int i = blockIdx.x * blockDim.x + threadIdx.x;  // 2048 threads
  long long v = t64[i];
  bool valid = (v == (long long)IGNORE_IDX) || (v >= 0 && v < (long long)VD);
  if (!valid) atomicAdd(badcnt, 1);
}

// ---------------------------------------------------------------------------
// fp32 -> bf16 bulk convert
// ---------------------------------------------------------------------------
__global__ void cvt_bf16_kernel(const float* __restrict__ in,
                                unsigned short* __restrict__ out, int n8) {
  int idx = blockIdx.x * blockDim.x + threadIdx.x;
  int stride = gridDim.x * blockDim.x;
  for (int i = idx; i < n8; i += stride) {
    float4 a = ((const float4*)in)[(size_t)2 * i];
    float4 b = ((const float4*)in)[(size_t)2 * i + 1];
    short8 o;
    o[0] = (short)f2bf(a.x);
    o[1] = (short)f2bf(a.y);
    o[2] = (short)f2bf(a.z);
    o[3] = (short)f2bf(a.w);
    o[4] = (short)f2bf(b.x);
    o[5] = (short)f2bf(b.y);
    o[6] = (short)f2bf(b.z);
    o[7] = (short)f2bf(b.w);
    ((short8*)out)[i] = o;
  }
}

// ---------------------------------------------------------------------------
// FAST PATH: 256x256 bf16 GEMM, BK=64, 128KB LDS double-buffer, 8-phase
// schedule with ONE-PHASE-EARLY ds_reads (counted-wait overlap) + counted
// vmcnt, fused with per-(rb,cb) sum(exp) and picked-target-logit.
//
// LDS: A/B = 4 slots x 8192 hw each (slot = buf*2 + half), FRAGMENT-ORDER
// (staging LDS-linear, per-lane global source permuted; ds_read lane-linear:
// zero bank conflicts).
//
// Per tile tau (4 phases), segments sigma_i before phase i's open barrier:
//   s1: RD bHi(tau)                      P1: acc[0..3][0..1] += aLo x bLo
//   s2: RD aHi(tau)                      P2: acc[0..3][2..3] += aLo x bHi
//   s3: STG B0,B1(tau+2); vmcnt(4)       P3: acc[4..7][2..3] += aHi x bHi
//   s4: STG A0,A1(tau+2); RD aLo,bLo'(tau+1)  P4: acc[4..7][0..1] += aHi x bLo
// Every read batch has >=1 full MFMA phase to drain before its consuming
// phase (compiler inserts minimal counted lgkm waits). vmcnt(4) sits before
// P3's OPEN barrier so all waves pass the gate before any wave's s4 reads
// of tile tau+1 (cross-wave safety). bLo is register-double-buffered (E/O);
// aLo/aHi/bHi lifetimes verified single-buffer safe. Slot WAR: B-slots
// staged at s3 (last read bHi retires at P2-open); A-slots at s4 (aHi
// retires P3-open). Ledger: steady outstanding 12 at s3 gate; vmcnt(4)
// drains exactly tile tau+1's 8 issues.
// ---------------------------------------------------------------------------
__global__ __launch_bounds__(512) void gemm_lse_8ph_kernel(
    const unsigned short* __restrict__ xbf,
    const unsigned short* __restrict__ wbf, const void* __restrict__ tgt,
    const int* __restrict__ badcnt, float* __restrict__ partialS,
    float* __restrict__ picked) {
  __shared__ unsigned short smem[65536];  // 128 KB
  unsigned short* ldsA = smem;            // 4 slots * 8192 hw
  unsigned short* ldsB = smem + 32768;

  const int t = threadIdx.x;

  // zero-init LDS (defensive: residual bug -> finite-wrong, never NaN)
  {
    uint4 z = make_uint4(0u, 0u, 0u, 0u);
#pragma unroll
    for (int i = 0; i < 16; i++) ((uint4*)smem)[t + i * 512] = z;
  }
  __syncthreads();

  // T1: bijective XCD swizzle (2000 % 8 == 0), rowblock-fast
  const int bid = blockIdx.x;
  const int cpx = (NRB2 * NCB2) >> 3;  // 250
  const int swz = (bid & 7) * cpx + (bid >> 3);
  const int rb = swz % NRB2;
  const int cb = swz / NRB2;
  const int row0 = rb * BM2;
  const int col0 = cb * BN2;

  const int lane = t & 63;
  const int w = t >> 6;    // 0..7
  const int wm = w >> 2;   // 0..1  (A half)
  const int wn = w & 3;    // 0..3
  const int bh = wn >> 1;  // B half
  const int bn4 = wn & 1;  // 64-col subrange within B half

  const int fr = lane & 15;
  const int kq = lane >> 4;  // 0..3

  // read-side LDS bases (fragment-order): lane-linear, conflict-free
  const unsigned short* pA0 = ldsA + (0 * 2 + wm) * 8192 + lane * 8;
  const unsigned short* pA1 = ldsA + (1 * 2 + wm) * 8192 + lane * 8;
  const unsigned short* pB0 =
      ldsB + (0 * 2 + bh) * 8192 + bn4 * 4096 + lane * 8;
  const unsigned short* pB1 =
      ldsB + (1 * 2 + bh) * 8192 + bn4 * 4096 + lane * 8;

  // staging: wave w stages 16-row block i=w of each half-tile; lane
  // l = kq*16+fr sources global (row = w*16 + (l&15), k = (l>>4)*8) and
  // lands at LDS linear l*16B -> fragment-order layout.
  const int srow = lane & 15;
  const int scol = (lane >> 4) * 8;
  const unsigned short* gA0 =
      xbf + (size_t)(row0 + 0 + w * 16 + srow) * HD + scol;
  const unsigned short* gA1 =
      xbf + (size_t)(row0 + 128 + w * 16 + srow) * HD + scol;
  const unsigned short* gB0 =
      wbf + (size_t)(col0 + 0 + w * 16 + srow) * HD + scol;
  const unsigned short* gB1 =
      wbf + (size_t)(col0 + 128 + w * 16 + srow) * HD + scol;

  unsigned short* dA = ldsA + w * 1024;  // wave's 2KB region within a slot
  unsigned short* dB = ldsB + w * 1024;

  f32x4 acc[8][4];
#pragma unroll
  for (int i = 0; i < 8; i++)
#pragma unroll
    for (int n = 0; n < 4; n++)
#pragma unroll
      for (int q = 0; q < 4; q++) acc[i][n][q] = 0.f;

  short8 aLo[4][2], aHi[4][2], bLoE[2][2], bLoO[2][2], bHi[2][2];

#define RDALO(P, D)                                    \
  _Pragma("unroll") for (int i = 0; i < 4; i++)        \
  _Pragma("unroll") for (int k2 = 0; k2 < 2; k2++)     \
      D[i][k2] = *(const short8*)((P) + i * 1024 + k2 * 512);

#define RDAHI(P, D)                                    \
  _Pragma("unroll") for (int i = 0; i < 4; i++)        \
  _Pragma("unroll") for (int k2 = 0; k2 < 2; k2++)     \
      D[i][k2] = *(const short8*)((P) + (i + 4) * 1024 + k2 * 512);

#define RDBLO(P, D)                                    \
  _Pragma("unroll") for (int n = 0; n < 2; n++)        \
  _Pragma("unroll") for (int k2 = 0; k2 < 2; k2++)     \
      D[n][k2] = *(const short8*)((P) + n * 1024 + k2 * 512);

#define RDBHI(P, D)                                    \
  _Pragma("unroll") for (int n = 0; n < 2; n++)        \
  _Pragma("unroll") for (int k2 = 0; k2 < 2; k2++)     \
      D[n][k2] = *(const short8*)((P) + (n + 2) * 1024 + k2 * 512);

#define PH(I0, N0, AF, BF)                                                    \
  __builtin_amdgcn_sched_barrier(0);                                          \
  __builtin_amdgcn_s_barrier();                                               \
  __builtin_amdgcn_sched_barrier(0);                                          \
  __builtin_amdgcn_s_setprio(1);                                              \
  _Pragma("unroll") for (int k2 = 0; k2 < 2; k2++)                            \
  _Pragma("unroll") for (int i = 0; i < 4; i++)                               \
  _Pragma("unroll") for (int n = 0; n < 2; n++)                               \
      acc[(I0) + i][(N0) + n] = __builtin_amdgcn_mfma_f32_16x16x32_bf16(      \
          AF[i][k2], BF[n][k2], acc[(I0) + i][(N0) + n], 0, 0, 0);            \
  __builtin_amdgcn_s_setprio(0);                                              \
  __builtin_amdgcn_sched_barrier(0);                                          \
  __builtin_amdgcn_s_barrier();                                               \
  __builtin_amdgcn_sched_barrier(0);

  // ---- prologue: stage tiles 0 and 1 fully (16 issues); drain tile0;
  //      barrier (cross-wave); read aLo,bLoE(0) ----
  STG2(gB0, 0, dB, 0);   // B0(0)
  STG2(gB1, 0, dB, 1);   // B1(0)
  STG2(gA0, 0, dA, 0);   // A0(0)
  STG2(gA1, 0, dA, 1);   // A1(0)
  STG2(gB0, 64, dB, 2);  // B0(1)
  STG2(gB1, 64, dB, 3);  // B1(1)
  STG2(gA0, 64, dA, 2);  // A0(1)
  STG2(gA1, 64, dA, 3);  // A1(1)
  asm volatile("s_waitcnt vmcnt(8)" ::: "memory");  // tile0 landed
  __builtin_amdgcn_s_barrier();                     // all waves past gate
  RDALO(pA0, aLo);
  RDBLO(pB0, bLoE);

  // ---- main loop: 2 tiles/iter; stages tiles kt+2 (s3/s4), kt+3 (s7/s8) --
  for (int kt = 0; kt + 3 < NKT; kt += 2) {
    // tile kt (buf0)
    RDBHI(pB0, bHi);            // s1
    PH(0, 0, aLo, bLoE);        // P1
    RDAHI(pA0, aHi);            // s2
    PH(0, 2, aLo, bHi);         // P2
    STG2(gB0, 128, dB, 0);      // s3: B0(kt+2)
    STG2(gB1, 128, dB, 1);      //     B1(kt+2)
    asm volatile("s_waitcnt vmcnt(4)" ::: "memory");  // tile kt+1 landed
    PH(4, 2, aHi, bHi);         // P3
    STG2(gA0, 128, dA, 0);      // s4: A0(kt+2)
    STG2(gA1, 128, dA, 1);      //     A1(kt+2)
    RDALO(pA1, aLo);            //     reads of tile kt+1 (safe: gate at s3)
    RDBLO(pB1, bLoO);
    PH(4, 0, aHi, bLoE);        // P4
    // tile kt+1 (buf1)
    RDBHI(pB1, bHi);            // s5
    PH(0, 0, aLo, bLoO);        // P5
    RDAHI(pA1, aHi);            // s6
    PH(0, 2, aLo, bHi);         // P6
    STG2(gB0, 192, dB, 2);      // s7: B0(kt+3)
    STG2(gB1, 192, dB, 3);      //     B1(kt+3)
    asm volatile("s_waitcnt vmcnt(4)" ::: "memory");  // tile kt+2 landed
    PH(4, 2, aHi, bHi);         // P7
    STG2(gA0, 192, dA, 2);      // s8: A0(kt+3)
    STG2(gA1, 192, dA, 3);      //     A1(kt+3)
    RDALO(pA0, aLo);            //     reads of tile kt+2
    RDBLO(pB0, bLoE);
    PH(4, 0, aHi, bLoO);        // P8
    gA0 += 128;  // advance 2 K-tiles
    gA1 += 128;
    gB0 += 128;
    gB1 += 128;
  }

  // ---- tail: tiles NKT-2 (buf0), NKT-1 (buf1); fully staged already ----
  {
    RDBHI(pB0, bHi);
    PH(0, 0, aLo, bLoE);
    RDAHI(pA0, aHi);
    PH(0, 2, aLo, bHi);
    asm volatile("s_waitcnt vmcnt(0)" ::: "memory");  // tile NKT-1 landed
    PH(4, 2, aHi, bHi);
    RDALO(pA1, aLo);
    RDBLO(pB1, bLoO);
    PH(4, 0, aHi, bLoE);
    RDBHI(pB1, bHi);
    PH(0, 0, aLo, bLoO);
    RDAHI(pA1, aHi);
    PH(0, 2, aLo, bHi);
    PH(4, 2, aHi, bHi);
    PH(4, 0, aHi, bLoO);
  }

  // ---- epilogue: per-row sum(exp) over this block's 256 cols ----
  // C/D layout: col = col0 + wn*64 + n*16 + fr ;
  //             row = row0 + wm*128 + i*16 + kq*4 + q
  __syncthreads();
  float* red = (float*)smem;  // [256 rows][4 wn] floats = 4KB
#pragma unroll
  for (int i = 0; i < 8; i++) {
#pragma unroll
    for (int q = 0; q < 4; q++) {
      float s = 0.f;
#pragma unroll
      for (int n = 0; n < 4; n++) s += __expf(acc[i][n][q]);
#pragma unroll
      for (int m = 1; m < 16; m <<= 1) s += __shfl_xor(s, m, 64);
      if (fr == 0) red[(wm * 128 + i * 16 + kq * 4 + q) * 4 + wn] = s;
    }
  }
  __syncthreads();
  if (t < 256) {
    float S = red[t * 4 + 0] + red[t * 4 + 1] + red[t * 4 + 2] + red[t * 4 + 3];
    partialS[(size_t)cb * BT + row0 + t] = S;
  }

  // ---- picked target logit (single writer per row across the grid) ----
  const bool is64 = (*badcnt == 0);
#pragma unroll
  for (int i = 0; i < 8; i++) {
#pragma unroll
    for (int q = 0; q < 4; q++) {
      int grow = row0 + wm * 128 + i * 16 + kq * 4 + q;
      long long tv = is64 ? ((const long long*)tgt)[grow]
                          : (long long)((const int*)tgt)[grow];
#pragma unroll
      for (int n = 0; n < 4; n++) {
        int gcol = col0 + wn * 64 + n * 16 + fr;
        if (tv == (long long)gcol) picked[grow] = acc[i][n][q];
      }
    }
  }
#undef RDALO
#undef RDAHI
#undef RDBLO
#undef RDBHI
#undef PH
}

// ---------------------------------------------------------------------------
// FALLBACK PATH (ws too small): fp32 inputs with on-the-fly cvt
// ---------------------------------------------------------------------------
__global__ __launch_bounds__(256) void gemm_lse_kernel(
    const float* __restrict__ x, const float* __restrict__ w,
    const void* __restrict__ tgt, const int* __restrict__ badcnt,
    float* __restrict__ partialS, float* __restrict__ picked) {
  __shared__ unsigned short As[BM][BKT];
  __shared__ unsigned short Bs[BN][BKT];

  const int bid = blockIdx.x;
  const int rb = bid % NRB;
  const int cb = bid / NRB;
  const int row0 = rb * BM;
  const int col0 = cb * BN;
  const int t = threadIdx.x;
  const int lane = t & 63;
  const int wave = t >> 6;
  const int wr = wave >> 1;
  const int wc = wave & 1;

  const int srow = t >> 3;
  const int scol = (t & 7) * 4;

  const float* xA = x + (size_t)row0 * HD;
  const float* wB = w + (size_t)col0 * HD;

  f32x4 acc[4][4];
#pragma unroll
  for (int i = 0; i < 4; i++)
#pragma unroll
    for (int j = 0; j < 4; j++)
#pragma unroll
      for (int q = 0; q < 4; q++) acc[i][j][q] = 0.f;

  float4 ra[4], rbv[4];

#define STAGE_LOAD(k0)                                                        \
  {                                                                           \
    _Pragma("unroll") for (int j = 0; j < 4; j++) {                           \
      ra[j] = *(const float4*)(xA + (size_t)(srow + j * 32) * HD + (k0) + scol); \
      rbv[j] = *(const float4*)(wB + (size_t)(srow + j * 32) * HD + (k0) + scol); \
    }                                                                         \
  }
#define STAGE_WRITE()                                                         \
  {                                                                           \
    _Pragma("unroll") for (int j = 0; j < 4; j++) {                           \
      ushort4 pa = make_ushort4(f2bf(ra[j].x), f2bf(ra[j].y), f2bf(ra[j].z),  \
                                f2bf(ra[j].w));                               \
      ushort4 pb = make_ushort4(f2bf(rbv[j].x), f2bf(rbv[j].y),               \
                                f2bf(rbv[j].z), f2bf(rbv[j].w));              \
      *(ushort4*)&As[srow + j * 32][scol] = pa;                               \
      *(ushort4*)&Bs[srow + j * 32][scol] = pb;                               \
    }                                                                         \
  }

  const int ks = (lane >> 4) * 8;
  const int fr = lane & 15;

  STAGE_LOAD(0);
  STAGE_WRITE();
  __syncthreads();

  for (int k0 = 0; k0 < HD; k0 += BKT) {
    const bool notlast = (k0 + BKT < HD);
    if (notlast) STAGE_LOAD(k0 + BKT);

    short8 af[4], bfv[4];
#pragma unroll
    for (int i = 0; i < 4; i++) {
      af[i] = *(const short8*)&As[wr * 64 + i * 16 + fr][ks];
      bfv[i] = *(const short8*)&Bs[wc * 64 + i * 16 + fr][ks];
    }
#pragma unroll
    for (int i = 0; i < 4; i++)
#pragma unroll
      for (int j = 0; j < 4; j++)
        acc[i][j] = __builtin_amdgcn_mfma_f32_16x16x32_bf16(af[i], bfv[j],
                                                            acc[i][j], 0, 0, 0);

    __syncthreads();
    if (notlast) STAGE_WRITE();
    __syncthreads();
  }
#undef STAGE_LOAD
#undef STAGE_WRITE

  float rsum[16];
#pragma unroll
  for (int mi = 0; mi < 4; mi++) {
#pragma unroll
    for (int r = 0; r < 4; r++) {
      float s = 0.f;
#pragma unroll
      for (int nj = 0; nj < 4; nj++) s += __expf(acc[mi][nj][r]);
      rsum[mi * 4 + r] = s;
    }
  }
#pragma unroll
  for (int m = 1; m < 16; m <<= 1) {
#pragma unroll
    for (int q = 0; q < 16; q++) rsum[q] += __shfl_xor(rsum[q], m, 64);
  }

  __syncthreads();
  float* red = (float*)&As[0][0];
  if (fr == 0) {
#pragma unroll
    for (int mi = 0; mi < 4; mi++)
#pragma unroll
      for (int r = 0; r < 4; r++)
        red[wave * 64 + mi * 16 + (lane >> 4) * 4 + r] = rsum[mi * 4 + r];
  }
  __syncthreads();

  if (t < BM) {
    int rl = t;
    int wrow = rl >> 6;
    float S = red[(wrow * 2 + 0) * 64 + (rl & 63)] +
              red[(wrow * 2 + 1) * 64 + (rl & 63)];
    partialS[(size_t)cb * BT + row0 + rl] = S;
  }

  const bool is64 = (*badcnt == 0);
#pragma unroll
  for (int mi = 0; mi < 4; mi++) {
#pragma unroll
    for (int r = 0; r < 4; r++) {
      int grow = row0 + wr * 64 + mi * 16 + ((lane >> 4) << 2) + r;
      long long tv = is64 ? ((const long long*)tgt)[grow]
                          : (long long)((const int*)tgt)[grow];
#pragma unroll
      for (int nj = 0; nj < 4; nj++) {
        int gcol = col0 + wc * 64 + nj * 16 + fr;
        if (tv == (long long)gcol) picked[grow] = acc[mi][nj][r];
      }
    }
  }
}

// ---------------------------------------------------------------------------
// Per-row: S = sum of ncb partials; nll = log(S) - picked.
// ---------------------------------------------------------------------------
__global__ void reduce_rows_kernel(const float* __restrict__ partialS,
                                   const float* __restrict__ picked,
                                   float* __restrict__ nll, int ncb) {
  int r = blockIdx.x * blockDim.x + threadIdx.x;
  if (r >= BT) return;
  float S = 0.f;
  for (int cb = 0; cb < ncb; cb++) S += partialS[(size_t)cb * BT + r];
  nll[r] = logf(fmaxf(S, 1e-37f)) - picked[r];
}

// ---------------------------------------------------------------------------
// Final: loss = sum(nll) / n_non_ignore
// ---------------------------------------------------------------------------
__global__ void reduce_final_kernel(const float* __restrict__ nll,
                                    const void* __restrict__ tgt,
                                    const int* __restrict__ badcnt,
                                    float* __restrict__ out) {
  __shared__ float ssum[256];
  __shared__ int scnt[256];
  int t = threadIdx.x;
  const bool is64 = (*badcnt == 0);
  float s = 0.f;
  int c = 0;
  for (int r = t; r < BT; r += 256) {
    s += nll[r];
    long long tv =
        is64 ? ((const long long*)tgt)[r] : (long long)((const int*)tgt)[r];
    c += (tv != (long long)IGNORE_IDX) ? 1 : 0;
  }
  ssum[t] = s;
  scnt[t] = c;
  __syncthreads();
  for (int o = 128; o > 0; o >>= 1) {
    if (t < o) {
      ssum[t] += ssum[t + o];
      scnt[t] += scnt[t + o];
    }
    __syncthreads();
  }
  if (t == 0) out[0] = ssum[0] / (float)scnt[0];
}

// ---------------------------------------------------------------------------
extern "C" void kernel_launch(void* const* d_in, const int* in_sizes, int n_in,
                              void* d_out, int out_size, void* d_ws,
                              size_t ws_size, hipStream_t stream) {
  const float* x = (const float*)d_in[0];
  const float* w = (const float*)d_in[1];
  const void* tgt = d_in[2];
  float* out = (float*)d_out;

  char* ws = (char*)d_ws;
  // ws layout:
  //   [0, offA)              : partialS (NCB*BT*4 = 4,096,000 B max)
  //   [offA, offA+16)        : badcnt flag (+pad)
  //   [offA+16, +BT*4)       : picked
  //   [.. +BT*4)             : nll
  //   [offX, +BT*HD*2)       : x as bf16
  //   [offW, +VD*HD*2)       : W as bf16
  const size_t offA = (size_t)NCB * BT * 4;
  float* partialS = (float*)ws;
  int* badcnt = (int*)(ws + offA);
  float* picked = (float*)(ws + offA + 16);
  float* nll = (float*)(ws + offA + 16 + (size_t)BT * 4);
  const size_t offX = offA + 16 + 2 * (size_t)BT * 4;
  const size_t offW = offX + (size_t)BT * HD * 2;
  const size_t need = offW + (size_t)VD * HD * 2;

  hipMemsetAsync(ws + offA, 0, 16 + (size_t)BT * 4, stream);

  detect_tgt_kernel<<<8, 256, 0, stream>>>((const long long*)tgt, badcnt);

  if (ws_size >= need) {
    unsigned short* xbf = (unsigned short*)(ws + offX);
    unsigned short* wbf = (unsigned short*)(ws + offW);
    cvt_bf16_kernel<<<2048, 256, 0, stream>>>(x, xbf, BT * HD / 8);
    cvt_bf16_kernel<<<2048, 256, 0, stream>>>(w, wbf, VD * HD / 8);
    gemm_lse_8ph_kernel<<<NRB2 * NCB2, 512, 0, stream>>>(xbf, wbf, tgt, badcnt,
                                                         partialS, picked);
    reduce_rows_kernel<<<BT / 256, 256, 0, stream>>>(partialS, picked, nll,
                                                     NCB2);
  } else {
    gemm_lse_kernel<<<NRB * NCB, 256, 0, stream>>>(x, w, tgt, badcnt, partialS,
                                                   picked);
    reduce_rows_kernel<<<BT / 256, 256, 0, stream>>>(partialS, picked, nll,
                                                     NCB);
  }

  reduce_final_kernel<<<1, 256, 0, stream>>>(nll, tgt, badcnt, out);
}

// Round 12
// 787.558 us; speedup vs baseline: 1.0850x; 1.0758x over previous
//
#include <hip/hip_runtime.h>
#include <hip/hip_bf16.h>

// Problem constants (from reference)
#define BT 4096
#define HD 2048
#define VD 32000
#define IGNORE_IDX (-100)

// ---- 256x256 GEMM geometry (fast path) ----
#define BM2 256
#define BN2 256
#define BK2 64
#define NRB2 (BT / BM2)  // 16
#define NCB2 (VD / BN2)  // 125
#define NKT (HD / BK2)   // 32

// ---- 128x128 fallback geometry (fp32 path) ----
#define BM 128
#define BN 128
#define BKT 32
#define NRB (BT / BM)  // 32
#define NCB (VD / BN)  // 250

using short8 = __attribute__((ext_vector_type(8))) short;
using f32x4 = __attribute__((ext_vector_type(4))) float;

__device__ __forceinline__ unsigned short f2bf(float f) {
  unsigned u = __float_as_uint(f);
  u = (u + 0x7fffu + ((u >> 16) & 1u)) >> 16;
  return (unsigned short)u;
}

// async global->LDS, 16B/lane; LDS dest = wave-uniform base + lane*16.
// offset param MUST stay 0 (R3/R4 NaN root cause) -- all offsets folded
// into the global pointer.
#define GL(SRC, DST)                                         \
  __builtin_amdgcn_global_load_lds(                          \
      (const __attribute__((address_space(1))) void*)(SRC),  \
      (__attribute__((address_space(3))) void*)(DST), 16, 0, 0)

// stage one half-tile (128 rows x 64 K bf16 = 16KB): 2 issues per thread.
#define STG2(GSRC, KOFF, DBASE, SLOT)                 \
  GL((GSRC) + (KOFF), (DBASE) + (SLOT)*8192);         \
  GL((GSRC) + (KOFF) + 32, (DBASE) + (SLOT)*8192 + 512)

// ---------------------------------------------------------------------------
// Detect whether target buffer is int64 or int32 (reads 16KB, safe either way)
// ---------------------------------------------------------------------------
__global__ void detect_tgt_kernel(const long long* __restrict__ t64,
                                  int* __restrict__ badcnt) {
  int i = blockIdx.x * blockDim.x + threadIdx.x;  // 2048 threads
  long long v = t64[i];
  bool valid = (v == (long long)IGNORE_IDX) || (v >= 0 && v < (long long)VD);
  if (!valid) atomicAdd(badcnt, 1);
}

// ---------------------------------------------------------------------------
// fp32 -> bf16 bulk convert
// ---------------------------------------------------------------------------
__global__ void cvt_bf16_kernel(const float* __restrict__ in,
                                unsigned short* __restrict__ out, int n8) {
  int idx = blockIdx.x * blockDim.x + threadIdx.x;
  int stride = gridDim.x * blockDim.x;
  for (int i = idx; i < n8; i += stride) {
    float4 a = ((const float4*)in)[(size_t)2 * i];
    float4 b = ((const float4*)in)[(size_t)2 * i + 1];
    short8 o;
    o[0] = (short)f2bf(a.x);
    o[1] = (short)f2bf(a.y);
    o[2] = (short)f2bf(a.z);
    o[3] = (short)f2bf(a.w);
    o[4] = (short)f2bf(b.x);
    o[5] = (short)f2bf(b.y);
    o[6] = (short)f2bf(b.z);
    o[7] = (short)f2bf(b.w);
    ((short8*)out)[i] = o;
  }
}

// ---------------------------------------------------------------------------
// FAST PATH: 256x256 bf16 GEMM, BK=64, 128KB LDS double-buffer, TWO-PHASE
// per K-tile schedule (32 MFMA/phase -- half the barrier events of the
// 4-phase version), counted vmcnt(4), fused epilogue.
//
// LDS: A/B = 4 slots x 8192 hw each (slot = buf*2 + half), FRAGMENT-ORDER
// (staging LDS-linear, per-lane global source permuted; ds_read lane-linear:
// zero bank conflicts; measured 0 in R6/R7).
//
// Per tile kt in buf0 (steady state; buf1 tile kt+1 symmetric):
//   [regs: aLo(kt), B(kt) read at prev iteration bottom]
//   PhA: open-bar, lgkm(0), 32 MFMA (i0..3 x n0..3), close-bar
//   STG B(kt+2)->dB0,dB1     (B(kt) reads retired at PhA-open)     +4
//   RD aHi(kt)  (8 ds_reads)
//   vmcnt(4)                  drains tile kt+1's 8 staging issues
//   PhB: open-bar, lgkm(0), 32 MFMA (i4..7 x n0..3), close-bar
//   STG A(kt+2)->dA0,dA1     (aHi(kt) reads retired at PhB-open)   +4
//   RD aLo(kt+1), B(kt+1)    (16 ds_reads; tile kt+1 landed: gate was
//                             vmcnt(4) before PhB-open + barrier)
// Ledger (steady): enter tile with 8 outstanding {B,A}(kt+1); +4 B -> 12;
// vmcnt(4) -> 4 {B(kt+2)}; +4 A -> 8. Prologue stages tiles 0,1 (16 issues),
// vmcnt(8) drains tile0. Tail uses vmcnt(0) once before tile30's PhB.
// All slot WAR/RAW hazards barrier-separated (audited).
// launch_bounds(512,2): min 2 waves/EU -> VGPR cap 256 (R8 spilled at the
// implicit 128 cap: WRITE_SIZE 2MB->18MB).
// ---------------------------------------------------------------------------
__global__ __launch_bounds__(512, 2) void gemm_lse_2ph_kernel(
    const unsigned short* __restrict__ xbf,
    const unsigned short* __restrict__ wbf, const void* __restrict__ tgt,
    const int* __restrict__ badcnt, float* __restrict__ partialS,
    float* __restrict__ picked) {
  __shared__ unsigned short smem[65536];  // 128 KB
  unsigned short* ldsA = smem;            // 4 slots * 8192 hw
  unsigned short* ldsB = smem + 32768;

  const int t = threadIdx.x;

  // zero-init LDS (defensive: residual bug -> finite-wrong, never NaN)
  {
    uint4 z = make_uint4(0u, 0u, 0u, 0u);
#pragma unroll
    for (int i = 0; i < 16; i++) ((uint4*)smem)[t + i * 512] = z;
  }
  __syncthreads();

  // T1: bijective XCD swizzle (2000 % 8 == 0), rowblock-fast
  const int bid = blockIdx.x;
  const int cpx = (NRB2 * NCB2) >> 3;  // 250
  const int swz = (bid & 7) * cpx + (bid >> 3);
  const int rb = swz % NRB2;
  const int cb = swz / NRB2;
  const int row0 = rb * BM2;
  const int col0 = cb * BN2;

  const int lane = t & 63;
  const int w = t >> 6;    // 0..7
  const int wm = w >> 2;   // 0..1  (A half)
  const int wn = w & 3;    // 0..3
  const int bh = wn >> 1;  // B half
  const int bn4 = wn & 1;  // 64-col subrange within B half

  const int fr = lane & 15;
  const int kq = lane >> 4;  // 0..3

  // read-side LDS bases (fragment-order): lane-linear, conflict-free
  const unsigned short* pA0 = ldsA + (0 * 2 + wm) * 8192 + lane * 8;
  const unsigned short* pA1 = ldsA + (1 * 2 + wm) * 8192 + lane * 8;
  const unsigned short* pB0 =
      ldsB + (0 * 2 + bh) * 8192 + bn4 * 4096 + lane * 8;
  const unsigned short* pB1 =
      ldsB + (1 * 2 + bh) * 8192 + bn4 * 4096 + lane * 8;

  // staging: wave w stages 16-row block i=w of each half-tile; lane
  // l = kq*16+fr sources global (row = w*16 + (l&15), k = (l>>4)*8) and
  // lands at LDS linear l*16B -> fragment-order layout.
  const int srow = lane & 15;
  const int scol = (lane >> 4) * 8;
  const unsigned short* gA0 =
      xbf + (size_t)(row0 + 0 + w * 16 + srow) * HD + scol;
  const unsigned short* gA1 =
      xbf + (size_t)(row0 + 128 + w * 16 + srow) * HD + scol;
  const unsigned short* gB0 =
      wbf + (size_t)(col0 + 0 + w * 16 + srow) * HD + scol;
  const unsigned short* gB1 =
      wbf + (size_t)(col0 + 128 + w * 16 + srow) * HD + scol;

  unsigned short* dA = ldsA + w * 1024;  // wave's 2KB region within a slot
  unsigned short* dB = ldsB + w * 1024;

  f32x4 acc[8][4];
#pragma unroll
  for (int i = 0; i < 8; i++)
#pragma unroll
    for (int n = 0; n < 4; n++)
#pragma unroll
      for (int q = 0; q < 4; q++) acc[i][n][q] = 0.f;

  short8 aLo[4][2], aHi[4][2], bF[4][2];

#define RDALO(P)                                       \
  _Pragma("unroll") for (int i = 0; i < 4; i++)        \
  _Pragma("unroll") for (int k2 = 0; k2 < 2; k2++)     \
      aLo[i][k2] = *(const short8*)((P) + i * 1024 + k2 * 512);

#define RDAHI(P)                                       \
  _Pragma("unroll") for (int i = 0; i < 4; i++)        \
  _Pragma("unroll") for (int k2 = 0; k2 < 2; k2++)     \
      aHi[i][k2] = *(const short8*)((P) + (i + 4) * 1024 + k2 * 512);

#define RDB(P)                                         \
  _Pragma("unroll") for (int n = 0; n < 4; n++)        \
  _Pragma("unroll") for (int k2 = 0; k2 < 2; k2++)     \
      bF[n][k2] = *(const short8*)((P) + n * 1024 + k2 * 512);

#define PH2(I0, AF)                                                           \
  __builtin_amdgcn_sched_barrier(0);                                          \
  __builtin_amdgcn_s_barrier();                                               \
  asm volatile("s_waitcnt lgkmcnt(0)" ::: "memory");                          \
  __builtin_amdgcn_sched_barrier(0);                                          \
  __builtin_amdgcn_s_setprio(1);                                              \
  _Pragma("unroll") for (int k2 = 0; k2 < 2; k2++)                            \
  _Pragma("unroll") for (int i = 0; i < 4; i++)                               \
  _Pragma("unroll") for (int n = 0; n < 4; n++)                               \
      acc[(I0) + i][n] = __builtin_amdgcn_mfma_f32_16x16x32_bf16(             \
          AF[i][k2], bF[n][k2], acc[(I0) + i][n], 0, 0, 0);                   \
  __builtin_amdgcn_s_setprio(0);                                              \
  __builtin_amdgcn_sched_barrier(0);                                          \
  __builtin_amdgcn_s_barrier();                                               \
  __builtin_amdgcn_sched_barrier(0);

  // ---- prologue: stage tiles 0 (first 8 issues) and 1; drain tile0;
  //      barrier; read aLo(0), B(0) ----
  STG2(gB0, 0, dB, 0);   // B0(0)
  STG2(gB1, 0, dB, 1);   // B1(0)
  STG2(gA0, 0, dA, 0);   // A0(0)
  STG2(gA1, 0, dA, 1);   // A1(0)
  STG2(gB0, 64, dB, 2);  // B0(1)
  STG2(gB1, 64, dB, 3);  // B1(1)
  STG2(gA0, 64, dA, 2);  // A0(1)
  STG2(gA1, 64, dA, 3);  // A1(1)
  asm volatile("s_waitcnt vmcnt(8)" ::: "memory");  // tile0 landed
  __builtin_amdgcn_s_barrier();                     // all waves past gate
  RDALO(pA0);
  RDB(pB0);

  // ---- main loop: 2 tiles/iter (buf0, buf1); stages tiles kt+2, kt+3 ----
  for (int kt = 0; kt + 3 < NKT; kt += 2) {
    // tile kt (buf0)
    PH2(0, aLo);            // PhA: i0..3 x all n
    STG2(gB0, 128, dB, 0);  // B0(kt+2)   (B(kt) reads retired at PhA-open)
    STG2(gB1, 128, dB, 1);  // B1(kt+2)
    RDAHI(pA0);
    asm volatile("s_waitcnt vmcnt(4)" ::: "memory");  // tile kt+1 landed
    PH2(4, aHi);            // PhB: i4..7 x all n
    STG2(gA0, 128, dA, 0);  // A0(kt+2)   (aHi(kt) retired at PhB-open)
    STG2(gA1, 128, dA, 1);  // A1(kt+2)
    RDALO(pA1);             // tile kt+1 reads (gate passed before PhB-open)
    RDB(pB1);
    // tile kt+1 (buf1)
    PH2(0, aLo);
    STG2(gB0, 192, dB, 2);  // B0(kt+3)
    STG2(gB1, 192, dB, 3);  // B1(kt+3)
    RDAHI(pA1);
    asm volatile("s_waitcnt vmcnt(4)" ::: "memory");  // tile kt+2 landed
    PH2(4, aHi);
    STG2(gA0, 192, dA, 2);  // A0(kt+3)
    STG2(gA1, 192, dA, 3);  // A1(kt+3)
    RDALO(pA0);             // tile kt+2 reads
    RDB(pB0);
    gA0 += 128;  // advance 2 K-tiles
    gA1 += 128;
    gB0 += 128;
    gB1 += 128;
  }

  // ---- tail: tiles NKT-2 (buf0), NKT-1 (buf1); fully staged already ----
  {
    PH2(0, aLo);            // tile 30 PhA
    RDAHI(pA0);
    asm volatile("s_waitcnt vmcnt(0)" ::: "memory");  // tile 31 landed
    PH2(4, aHi);            // tile 30 PhB
    RDALO(pA1);
    RDB(pB1);
    PH2(0, aLo);            // tile 31 PhA
    RDAHI(pA1);
    PH2(4, aHi);            // tile 31 PhB
  }

  // ---- epilogue: per-row sum(exp) over this block's 256 cols ----
  // C/D layout: col = col0 + wn*64 + n*16 + fr ;
  //             row = row0 + wm*128 + i*16 + kq*4 + q
  __syncthreads();
  float* red = (float*)smem;  // [256 rows][4 wn] floats = 4KB
#pragma unroll
  for (int i = 0; i < 8; i++) {
#pragma unroll
    for (int q = 0; q < 4; q++) {
      float s = 0.f;
#pragma unroll
      for (int n = 0; n < 4; n++) s += __expf(acc[i][n][q]);
#pragma unroll
      for (int m = 1; m < 16; m <<= 1) s += __shfl_xor(s, m, 64);
      if (fr == 0) red[(wm * 128 + i * 16 + kq * 4 + q) * 4 + wn] = s;
    }
  }
  __syncthreads();
  if (t < 256) {
    float S = red[t * 4 + 0] + red[t * 4 + 1] + red[t * 4 + 2] + red[t * 4 + 3];
    partialS[(size_t)cb * BT + row0 + t] = S;
  }

  // ---- picked target logit (single writer per row across the grid) ----
  const bool is64 = (*badcnt == 0);
#pragma unroll
  for (int i = 0; i < 8; i++) {
#pragma unroll
    for (int q = 0; q < 4; q++) {
      int grow = row0 + wm * 128 + i * 16 + kq * 4 + q;
      long long tv = is64 ? ((const long long*)tgt)[grow]
                          : (long long)((const int*)tgt)[grow];
#pragma unroll
      for (int n = 0; n < 4; n++) {
        int gcol = col0 + wn * 64 + n * 16 + fr;
        if (tv == (long long)gcol) picked[grow] = acc[i][n][q];
      }
    }
  }
#undef RDALO
#undef RDAHI
#undef RDB
#undef PH2
}

// ---------------------------------------------------------------------------
// FALLBACK PATH (ws too small): fp32 inputs with on-the-fly cvt
// ---------------------------------------------------------------------------
__global__ __launch_bounds__(256) void gemm_lse_kernel(
    const float* __restrict__ x, const float* __restrict__ w,
    const void* __restrict__ tgt, const int* __restrict__ badcnt,
    float* __restrict__ partialS, float* __restrict__ picked) {
  __shared__ unsigned short As[BM][BKT];
  __shared__ unsigned short Bs[BN][BKT];

  const int bid = blockIdx.x;
  const int rb = bid % NRB;
  const int cb = bid / NRB;
  const int row0 = rb * BM;
  const int col0 = cb * BN;
  const int t = threadIdx.x;
  const int lane = t & 63;
  const int wave = t >> 6;
  const int wr = wave >> 1;
  const int wc = wave & 1;

  const int srow = t >> 3;
  const int scol = (t & 7) * 4;

  const float* xA = x + (size_t)row0 * HD;
  const float* wB = w + (size_t)col0 * HD;

  f32x4 acc[4][4];
#pragma unroll
  for (int i = 0; i < 4; i++)
#pragma unroll
    for (int j = 0; j < 4; j++)
#pragma unroll
      for (int q = 0; q < 4; q++) acc[i][j][q] = 0.f;

  float4 ra[4], rbv[4];

#define STAGE_LOAD(k0)                                                        \
  {                                                                           \
    _Pragma("unroll") for (int j = 0; j < 4; j++) {                           \
      ra[j] = *(const float4*)(xA + (size_t)(srow + j * 32) * HD + (k0) + scol); \
      rbv[j] = *(const float4*)(wB + (size_t)(srow + j * 32) * HD + (k0) + scol); \
    }                                                                         \
  }
#define STAGE_WRITE()                                                         \
  {                                                                           \
    _Pragma("unroll") for (int j = 0; j < 4; j++) {                           \
      ushort4 pa = make_ushort4(f2bf(ra[j].x), f2bf(ra[j].y), f2bf(ra[j].z),  \
                                f2bf(ra[j].w));                               \
      ushort4 pb = make_ushort4(f2bf(rbv[j].x), f2bf(rbv[j].y),               \
                                f2bf(rbv[j].z), f2bf(rbv[j].w));              \
      *(ushort4*)&As[srow + j * 32][scol] = pa;                               \
      *(ushort4*)&Bs[srow + j * 32][scol] = pb;                               \
    }                                                                         \
  }

  const int ks = (lane >> 4) * 8;
  const int fr = lane & 15;

  STAGE_LOAD(0);
  STAGE_WRITE();
  __syncthreads();

  for (int k0 = 0; k0 < HD; k0 += BKT) {
    const bool notlast = (k0 + BKT < HD);
    if (notlast) STAGE_LOAD(k0 + BKT);

    short8 af[4], bfv[4];
#pragma unroll
    for (int i = 0; i < 4; i++) {
      af[i] = *(const short8*)&As[wr * 64 + i * 16 + fr][ks];
      bfv[i] = *(const short8*)&Bs[wc * 64 + i * 16 + fr][ks];
    }
#pragma unroll
    for (int i = 0; i < 4; i++)
#pragma unroll
      for (int j = 0; j < 4; j++)
        acc[i][j] = __builtin_amdgcn_mfma_f32_16x16x32_bf16(af[i], bfv[j],
                                                            acc[i][j], 0, 0, 0);

    __syncthreads();
    if (notlast) STAGE_WRITE();
    __syncthreads();
  }
#undef STAGE_LOAD
#undef STAGE_WRITE

  float rsum[16];
#pragma unroll
  for (int mi = 0; mi < 4; mi++) {
#pragma unroll
    for (int r = 0; r < 4; r++) {
      float s = 0.f;
#pragma unroll
      for (int nj = 0; nj < 4; nj++) s += __expf(acc[mi][nj][r]);
      rsum[mi * 4 + r] = s;
    }
  }
#pragma unroll
  for (int m = 1; m < 16; m <<= 1) {
#pragma unroll
    for (int q = 0; q < 16; q++) rsum[q] += __shfl_xor(rsum[q], m, 64);
  }

  __syncthreads();
  float* red = (float*)&As[0][0];
  if (fr == 0) {
#pragma unroll
    for (int mi = 0; mi < 4; mi++)
#pragma unroll
      for (int r = 0; r < 4; r++)
        red[wave * 64 + mi * 16 + (lane >> 4) * 4 + r] = rsum[mi * 4 + r];
  }
  __syncthreads();

  if (t < BM) {
    int rl = t;
    int wrow = rl >> 6;
    float S = red[(wrow * 2 + 0) * 64 + (rl & 63)] +
              red[(wrow * 2 + 1) * 64 + (rl & 63)];
    partialS[(size_t)cb * BT + row0 + rl] = S;
  }

  const bool is64 = (*badcnt == 0);
#pragma unroll
  for (int mi = 0; mi < 4; mi++) {
#pragma unroll
    for (int r = 0; r < 4; r++) {
      int grow = row0 + wr * 64 + mi * 16 + ((lane >> 4) << 2) + r;
      long long tv = is64 ? ((const long long*)tgt)[grow]
                          : (long long)((const int*)tgt)[grow];
#pragma unroll
      for (int nj = 0; nj < 4; nj++) {
        int gcol = col0 + wc * 64 + nj * 16 + fr;
        if (tv == (long long)gcol) picked[grow] = acc[mi][nj][r];
      }
    }
  }
}

// ---------------------------------------------------------------------------
// Per-row: S = sum of ncb partials; nll = log(S) - picked.
// ---------------------------------------------------------------------------
__global__ void reduce_rows_kernel(const float* __restrict__ partialS,
                                   const float* __restrict__ picked,
                                   float* __restrict__ nll, int ncb) {
  int r = blockIdx.x * blockDim.x + threadIdx.x;
  if (r >= BT) return;
  float S = 0.f;
  for (int cb = 0; cb < ncb; cb++) S += partialS[(size_t)cb * BT + r];
  nll[r] = logf(fmaxf(S, 1e-37f)) - picked[r];
}

// ---------------------------------------------------------------------------
// Final: loss = sum(nll) / n_non_ignore
// ---------------------------------------------------------------------------
__global__ void reduce_final_kernel(const float* __restrict__ nll,
                                    const void* __restrict__ tgt,
                                    const int* __restrict__ badcnt,
                                    float* __restrict__ out) {
  __shared__ float ssum[256];
  __shared__ int scnt[256];
  int t = threadIdx.x;
  const bool is64 = (*badcnt == 0);
  float s = 0.f;
  int c = 0;
  for (int r = t; r < BT; r += 256) {
    s += nll[r];
    long long tv =
        is64 ? ((const long long*)tgt)[r] : (long long)((const int*)tgt)[r];
    c += (tv != (long long)IGNORE_IDX) ? 1 : 0;
  }
  ssum[t] = s;
  scnt[t] = c;
  __syncthreads();
  for (int o = 128; o > 0; o >>= 1) {
    if (t < o) {
      ssum[t] += ssum[t + o];
      scnt[t] += scnt[t + o];
    }
    __syncthreads();
  }
  if (t == 0) out[0] = ssum[0] / (float)scnt[0];
}

// ---------------------------------------------------------------------------
extern "C" void kernel_launch(void* const* d_in, const int* in_sizes, int n_in,
                              void* d_out, int out_size, void* d_ws,
                              size_t ws_size, hipStream_t stream) {
  const float* x = (const float*)d_in[0];
  const float* w = (const float*)d_in[1];
  const void* tgt = d_in[2];
  float* out = (float*)d_out;

  char* ws = (char*)d_ws;
  // ws layout:
  //   [0, offA)              : partialS (NCB*BT*4 = 4,096,000 B max)
  //   [offA, offA+16)        : badcnt flag (+pad)
  //   [offA+16, +BT*4)       : picked
  //   [.. +BT*4)             : nll
  //   [offX, +BT*HD*2)       : x as bf16
  //   [offW, +VD*HD*2)       : W as bf16
  const size_t offA = (size_t)NCB * BT * 4;
  float* partialS = (float*)ws;
  int* badcnt = (int*)(ws + offA);
  float* picked = (float*)(ws + offA + 16);
  float* nll = (float*)(ws + offA + 16 + (size_t)BT * 4);
  const size_t offX = offA + 16 + 2 * (size_t)BT * 4;
  const size_t offW = offX + (size_t)BT * HD * 2;
  const size_t need = offW + (size_t)VD * HD * 2;

  hipMemsetAsync(ws + offA, 0, 16 + (size_t)BT * 4, stream);

  detect_tgt_kernel<<<8, 256, 0, stream>>>((const long long*)tgt, badcnt);

  if (ws_size >= need) {
    unsigned short* xbf = (unsigned short*)(ws + offX);
    unsigned short* wbf = (unsigned short*)(ws + offW);
    cvt_bf16_kernel<<<2048, 256, 0, stream>>>(x, xbf, BT * HD / 8);
    cvt_bf16_kernel<<<2048, 256, 0, stream>>>(w, wbf, VD * HD / 8);
    gemm_lse_2ph_kernel<<<NRB2 * NCB2, 512, 0, stream>>>(xbf, wbf, tgt, badcnt,
                                                         partialS, picked);
    reduce_rows_kernel<<<BT / 256, 256, 0, stream>>>(partialS, picked, nll,
                                                     NCB2);
  } else {
    gemm_lse_kernel<<<NRB * NCB, 256, 0, stream>>>(x, w, tgt, badcnt, partialS,
                                                   picked);
    reduce_rows_kernel<<<BT / 256, 256, 0, stream>>>(partialS, picked, nll,
                                                     NCB);
  }

  reduce_final_kernel<<<1, 256, 0, stream>>>(nll, tgt, badcnt, out);
}

// Round 13
// 752.818 us; speedup vs baseline: 1.1351x; 1.0461x over previous
//
#include <hip/hip_runtime.h>
#include <hip/hip_bf16.h>

// Problem constants (from reference)
#define BT 4096
#define HD 2048
#define VD 32000
#define IGNORE_IDX (-100)

// ---- 256x256 GEMM geometry (fast path) ----
#define BM2 256
#define BN2 256
#define BK2 64
#define NRB2 (BT / BM2)  // 16
#define NCB2 (VD / BN2)  // 125
#define NKT (HD / BK2)   // 32

// ---- 128x128 fallback geometry (fp32 path) ----
#define BM 128
#define BN 128
#define BKT 32
#define NRB (BT / BM)  // 32
#define NCB (VD / BN)  // 250

using short8 = __attribute__((ext_vector_type(8))) short;
using f32x4 = __attribute__((ext_vector_type(4))) float;

__device__ __forceinline__ unsigned short f2bf(float f) {
  unsigned u = __float_as_uint(f);
  u = (u + 0x7fffu + ((u >> 16) & 1u)) >> 16;
  return (unsigned short)u;
}

// async global->LDS, 16B/lane; LDS dest = wave-uniform base + lane*16.
// offset param MUST stay 0 (R3/R4 NaN root cause) -- all offsets folded
// into the global pointer.
#define GL(SRC, DST)                                         \
  __builtin_amdgcn_global_load_lds(                          \
      (const __attribute__((address_space(1))) void*)(SRC),  \
      (__attribute__((address_space(3))) void*)(DST), 16, 0, 0)

// stage one half-tile (128 rows x 64 K bf16 = 16KB): 2 issues per thread.
#define STG2(GSRC, KOFF, DBASE, SLOT)                 \
  GL((GSRC) + (KOFF), (DBASE) + (SLOT)*8192);         \
  GL((GSRC) + (KOFF) + 32, (DBASE) + (SLOT)*8192 + 512)

// ---------------------------------------------------------------------------
// Detect whether target buffer is int64 or int32 (reads 16KB, safe either way)
// ---------------------------------------------------------------------------
__global__ void detect_tgt_kernel(const long long* __restrict__ t64,
                                  int* __restrict__ badcnt) {
  int i = blockIdx.x * blockDim.x + threadIdx.x;  // 2048 threads
  long long v = t64[i];
  bool valid = (v == (long long)IGNORE_IDX) || (v >= 0 && v < (long long)VD);
  if (!valid) atomicAdd(badcnt, 1);
}

// ---------------------------------------------------------------------------
// fp32 -> bf16 bulk convert
// ---------------------------------------------------------------------------
__global__ void cvt_bf16_kernel(const float* __restrict__ in,
                                unsigned short* __restrict__ out, int n8) {
  int idx = blockIdx.x * blockDim.x + threadIdx.x;
  int stride = gridDim.x * blockDim.x;
  for (int i = idx; i < n8; i += stride) {
    float4 a = ((const float4*)in)[(size_t)2 * i];
    float4 b = ((const float4*)in)[(size_t)2 * i + 1];
    short8 o;
    o[0] = (short)f2bf(a.x);
    o[1] = (short)f2bf(a.y);
    o[2] = (short)f2bf(a.z);
    o[3] = (short)f2bf(a.w);
    o[4] = (short)f2bf(b.x);
    o[5] = (short)f2bf(b.y);
    o[6] = (short)f2bf(b.z);
    o[7] = (short)f2bf(b.w);
    ((short8*)out)[i] = o;
  }
}

// ---------------------------------------------------------------------------
// FAST PATH: 256x256 bf16 GEMM, BK=64, 128KB LDS double-buffer, 4 phases per
// K-tile with SPREAD reads (m201 pattern: 12/8/4/0 per segment, each batch
// drained one phase later under MFMA), counted vmcnt(6), fused epilogue.
//
// LDS: A/B = 4 slots x 8192 hw (slot = buf*2 + half), FRAGMENT-ORDER
// (staging LDS-linear, per-lane global source permuted; ds_read lane-linear:
// zero bank conflicts, measured 0 in R6/R7/R12).
//
// Per tile kt (buf0 shown; buf1 symmetric), segments before each phase:
//   s1: RD aLo(8) + bLo(4); STG B1(kt+1)     P1: acc[0-3][0-1] aLo x bLo
//   s2: RD aHi(8);          STG A0(kt+2)     P2: acc[4-7][0-1] aHi x bLo
//   s3: RD bHi(4);          STG A1(kt+2)     P3: acc[4-7][2-3] aHi x bHi
//   s4:                     STG B0(kt+2);
//       vmcnt(6)                              P4: acc[0-3][2-3] aLo x bHi
// Fragment lifetimes stay inside the tile (peak 80 regs: aLo+aHi+bHi) --
// fits the ~128 arch-VGPR half of the unified file at 2 waves/SIMD (acc=128
// AGPR). R11/R12 spilled because lifetimes crossed the tile boundary.
// WAR: all slot overwrites barrier-separated EXCEPT A0@s2 vs same-segment
// aHi reads -- safe by latency gap (gload arrival >=200cy >> ds_read drain
// <=60cy; the m201-verified pattern). vmcnt(6)@s4 = 3 half-tiles in flight;
// drains exactly through B1(kt+1) (chronology: A0,A1,B0(kt+1)@kt-1, then
// B1(kt+1)@kt-s1, then 6 newer issues).
// ---------------------------------------------------------------------------
__global__ __launch_bounds__(512, 2) void gemm_lse_8ph_kernel(
    const unsigned short* __restrict__ xbf,
    const unsigned short* __restrict__ wbf, const void* __restrict__ tgt,
    const int* __restrict__ badcnt, float* __restrict__ partialS,
    float* __restrict__ picked) {
  __shared__ unsigned short smem[65536];  // 128 KB
  unsigned short* ldsA = smem;            // 4 slots * 8192 hw
  unsigned short* ldsB = smem + 32768;

  const int t = threadIdx.x;

  // zero-init LDS (defensive: residual bug -> finite-wrong, never NaN)
  {
    uint4 z = make_uint4(0u, 0u, 0u, 0u);
#pragma unroll
    for (int i = 0; i < 16; i++) ((uint4*)smem)[t + i * 512] = z;
  }
  __syncthreads();

  // T1: bijective XCD swizzle (2000 % 8 == 0), rowblock-fast
  const int bid = blockIdx.x;
  const int cpx = (NRB2 * NCB2) >> 3;  // 250
  const int swz = (bid & 7) * cpx + (bid >> 3);
  const int rb = swz % NRB2;
  const int cb = swz / NRB2;
  const int row0 = rb * BM2;
  const int col0 = cb * BN2;

  const int lane = t & 63;
  const int w = t >> 6;    // 0..7
  const int wm = w >> 2;   // 0..1  (A half)
  const int wn = w & 3;    // 0..3
  const int bh = wn >> 1;  // B half
  const int bn4 = wn & 1;  // 64-col subrange within B half

  const int fr = lane & 15;
  const int kq = lane >> 4;  // 0..3

  // read-side LDS bases (fragment-order): lane-linear, conflict-free
  const unsigned short* pA0 = ldsA + (0 * 2 + wm) * 8192 + lane * 8;
  const unsigned short* pA1 = ldsA + (1 * 2 + wm) * 8192 + lane * 8;
  const unsigned short* pB0 =
      ldsB + (0 * 2 + bh) * 8192 + bn4 * 4096 + lane * 8;
  const unsigned short* pB1 =
      ldsB + (1 * 2 + bh) * 8192 + bn4 * 4096 + lane * 8;

  // staging: wave w stages 16-row block i=w of each half-tile; lane
  // l = kq*16+fr sources global (row = w*16 + (l&15), k = (l>>4)*8) and
  // lands at LDS linear l*16B -> fragment-order layout.
  const int srow = lane & 15;
  const int scol = (lane >> 4) * 8;
  const unsigned short* gA0 =
      xbf + (size_t)(row0 + 0 + w * 16 + srow) * HD + scol;
  const unsigned short* gA1 =
      xbf + (size_t)(row0 + 128 + w * 16 + srow) * HD + scol;
  const unsigned short* gB0 =
      wbf + (size_t)(col0 + 0 + w * 16 + srow) * HD + scol;
  const unsigned short* gB1 =
      wbf + (size_t)(col0 + 128 + w * 16 + srow) * HD + scol;

  unsigned short* dA = ldsA + w * 1024;  // wave's 2KB region within a slot
  unsigned short* dB = ldsB + w * 1024;

  f32x4 acc[8][4];
#pragma unroll
  for (int i = 0; i < 8; i++)
#pragma unroll
    for (int n = 0; n < 4; n++)
#pragma unroll
      for (int q = 0; q < 4; q++) acc[i][n][q] = 0.f;

  short8 aLo[4][2], aHi[4][2], bLo[2][2], bHi[2][2];

#define RDALO(P)                                       \
  _Pragma("unroll") for (int i = 0; i < 4; i++)        \
  _Pragma("unroll") for (int k2 = 0; k2 < 2; k2++)     \
      aLo[i][k2] = *(const short8*)((P) + i * 1024 + k2 * 512);

#define RDAHI(P)                                       \
  _Pragma("unroll") for (int i = 0; i < 4; i++)        \
  _Pragma("unroll") for (int k2 = 0; k2 < 2; k2++)     \
      aHi[i][k2] = *(const short8*)((P) + (i + 4) * 1024 + k2 * 512);

#define RDBLO(P)                                       \
  _Pragma("unroll") for (int n = 0; n < 2; n++)        \
  _Pragma("unroll") for (int k2 = 0; k2 < 2; k2++)     \
      bLo[n][k2] = *(const short8*)((P) + n * 1024 + k2 * 512);

#define RDBHI(P)                                       \
  _Pragma("unroll") for (int n = 0; n < 2; n++)        \
  _Pragma("unroll") for (int k2 = 0; k2 < 2; k2++)     \
      bHi[n][k2] = *(const short8*)((P) + (n + 2) * 1024 + k2 * 512);

#define PH(I0, N0, AF, BF)                                                    \
  __builtin_amdgcn_sched_barrier(0);                                          \
  __builtin_amdgcn_s_barrier();                                               \
  asm volatile("s_waitcnt lgkmcnt(0)" ::: "memory");                          \
  __builtin_amdgcn_sched_barrier(0);                                          \
  __builtin_amdgcn_s_setprio(1);                                              \
  _Pragma("unroll") for (int k2 = 0; k2 < 2; k2++)                            \
  _Pragma("unroll") for (int i = 0; i < 4; i++)                               \
  _Pragma("unroll") for (int n = 0; n < 2; n++)                               \
      acc[(I0) + i][(N0) + n] = __builtin_amdgcn_mfma_f32_16x16x32_bf16(      \
          AF[i][k2], BF[n][k2], acc[(I0) + i][(N0) + n], 0, 0, 0);            \
  __builtin_amdgcn_s_setprio(0);                                              \
  __builtin_amdgcn_sched_barrier(0);                                          \
  __builtin_amdgcn_s_barrier();                                               \
  __builtin_amdgcn_sched_barrier(0);

  // ---- prologue: tile0 fully + A0/A1/B0 of tile1 (14 issues); vmcnt(6)
  //      drains tile0; B1(1) is staged at tile0's s1 per the steady stream --
  STG2(gA0, 0, dA, 0);   // A0(0) buf0
  STG2(gA1, 0, dA, 1);   // A1(0)
  STG2(gB0, 0, dB, 0);   // B0(0)
  STG2(gB1, 0, dB, 1);   // B1(0)
  STG2(gA0, 64, dA, 2);  // A0(1) buf1
  STG2(gA1, 64, dA, 3);  // A1(1)
  STG2(gB0, 64, dB, 2);  // B0(1)
  asm volatile("s_waitcnt vmcnt(6)" ::: "memory");  // tile0 landed
  __builtin_amdgcn_s_barrier();

  // ---- main loop: 2 tiles/iter (buf0, buf1) ----
  for (int kt = 0; kt + 3 < NKT; kt += 2) {
    // tile kt (buf0)
    RDALO(pA0);
    RDBLO(pB0);
    STG2(gB1, 64, dB, 3);   // B1(kt+1) -> buf1 half1
    PH(0, 0, aLo, bLo);     // P1: lo x lo
    RDAHI(pA0);
    STG2(gA0, 128, dA, 0);  // A0(kt+2) (latency-gap safe vs aHi reads)
    PH(4, 0, aHi, bLo);     // P2: hi x lo
    RDBHI(pB0);
    STG2(gA1, 128, dA, 1);  // A1(kt+2) (aHi reads retired at P2-open)
    PH(4, 2, aHi, bHi);     // P3: hi x hi
    STG2(gB0, 128, dB, 0);  // B0(kt+2) (bLo reads retired at P1-open)
    asm volatile("s_waitcnt vmcnt(6)" ::: "memory");  // tile kt+1 landed
    PH(0, 2, aLo, bHi);     // P4: lo x hi
    // tile kt+1 (buf1)
    RDALO(pA1);
    RDBLO(pB1);
    STG2(gB1, 128, dB, 1);  // B1(kt+2) -> buf0 half1
    PH(0, 0, aLo, bLo);
    RDAHI(pA1);
    STG2(gA0, 192, dA, 2);  // A0(kt+3)
    PH(4, 0, aHi, bLo);
    RDBHI(pB1);
    STG2(gA1, 192, dA, 3);  // A1(kt+3)
    PH(4, 2, aHi, bHi);
    STG2(gB0, 192, dB, 2);  // B0(kt+3)
    asm volatile("s_waitcnt vmcnt(6)" ::: "memory");  // tile kt+2 landed
    PH(0, 2, aLo, bHi);
    gA0 += 128;  // advance 2 K-tiles
    gA1 += 128;
    gB0 += 128;
    gB1 += 128;
  }

  // ---- tail: tiles NKT-2 (buf0), NKT-1 (buf1) ----
  {
    RDALO(pA0);
    RDBLO(pB0);
    STG2(gB1, 64, dB, 3);  // B1(NKT-1)
    PH(0, 0, aLo, bLo);
    RDAHI(pA0);
    PH(4, 0, aHi, bLo);
    RDBHI(pB0);
    PH(4, 2, aHi, bHi);
    asm volatile("s_waitcnt vmcnt(0)" ::: "memory");  // tile NKT-1 landed
    PH(0, 2, aLo, bHi);
    RDALO(pA1);
    RDBLO(pB1);
    PH(0, 0, aLo, bLo);
    RDAHI(pA1);
    PH(4, 0, aHi, bLo);
    RDBHI(pB1);
    PH(4, 2, aHi, bHi);
    PH(0, 2, aLo, bHi);
  }

  // ---- epilogue: per-row sum(exp) over this block's 256 cols ----
  // C/D layout: col = col0 + wn*64 + n*16 + fr ;
  //             row = row0 + wm*128 + i*16 + kq*4 + q
  __syncthreads();
  float* red = (float*)smem;  // [256 rows][4 wn] floats = 4KB
#pragma unroll
  for (int i = 0; i < 8; i++) {
#pragma unroll
    for (int q = 0; q < 4; q++) {
      float s = 0.f;
#pragma unroll
      for (int n = 0; n < 4; n++) s += __expf(acc[i][n][q]);
#pragma unroll
      for (int m = 1; m < 16; m <<= 1) s += __shfl_xor(s, m, 64);
      if (fr == 0) red[(wm * 128 + i * 16 + kq * 4 + q) * 4 + wn] = s;
    }
  }
  __syncthreads();
  if (t < 256) {
    float S = red[t * 4 + 0] + red[t * 4 + 1] + red[t * 4 + 2] + red[t * 4 + 3];
    partialS[(size_t)cb * BT + row0 + t] = S;
  }

  // ---- picked target logit (single writer per row across the grid) ----
  const bool is64 = (*badcnt == 0);
#pragma unroll
  for (int i = 0; i < 8; i++) {
#pragma unroll
    for (int q = 0; q < 4; q++) {
      int grow = row0 + wm * 128 + i * 16 + kq * 4 + q;
      long long tv = is64 ? ((const long long*)tgt)[grow]
                          : (long long)((const int*)tgt)[grow];
#pragma unroll
      for (int n = 0; n < 4; n++) {
        int gcol = col0 + wn * 64 + n * 16 + fr;
        if (tv == (long long)gcol) picked[grow] = acc[i][n][q];
      }
    }
  }
#undef RDALO
#undef RDAHI
#undef RDBLO
#undef RDBHI
#undef PH
}

// ---------------------------------------------------------------------------
// FALLBACK PATH (ws too small): fp32 inputs with on-the-fly cvt
// ---------------------------------------------------------------------------
__global__ __launch_bounds__(256) void gemm_lse_kernel(
    const float* __restrict__ x, const float* __restrict__ w,
    const void* __restrict__ tgt, const int* __restrict__ badcnt,
    float* __restrict__ partialS, float* __restrict__ picked) {
  __shared__ unsigned short As[BM][BKT];
  __shared__ unsigned short Bs[BN][BKT];

  const int bid = blockIdx.x;
  const int rb = bid % NRB;
  const int cb = bid / NRB;
  const int row0 = rb * BM;
  const int col0 = cb * BN;
  const int t = threadIdx.x;
  const int lane = t & 63;
  const int wave = t >> 6;
  const int wr = wave >> 1;
  const int wc = wave & 1;

  const int srow = t >> 3;
  const int scol = (t & 7) * 4;

  const float* xA = x + (size_t)row0 * HD;
  const float* wB = w + (size_t)col0 * HD;

  f32x4 acc[4][4];
#pragma unroll
  for (int i = 0; i < 4; i++)
#pragma unroll
    for (int j = 0; j < 4; j++)
#pragma unroll
      for (int q = 0; q < 4; q++) acc[i][j][q] = 0.f;

  float4 ra[4], rbv[4];

#define STAGE_LOAD(k0)                                                        \
  {                                                                           \
    _Pragma("unroll") for (int j = 0; j < 4; j++) {                           \
      ra[j] = *(const float4*)(xA + (size_t)(srow + j * 32) * HD + (k0) + scol); \
      rbv[j] = *(const float4*)(wB + (size_t)(srow + j * 32) * HD + (k0) + scol); \
    }                                                                         \
  }
#define STAGE_WRITE()                                                         \
  {                                                                           \
    _Pragma("unroll") for (int j = 0; j < 4; j++) {                           \
      ushort4 pa = make_ushort4(f2bf(ra[j].x), f2bf(ra[j].y), f2bf(ra[j].z),  \
                                f2bf(ra[j].w));                               \
      ushort4 pb = make_ushort4(f2bf(rbv[j].x), f2bf(rbv[j].y),               \
                                f2bf(rbv[j].z), f2bf(rbv[j].w));              \
      *(ushort4*)&As[srow + j * 32][scol] = pa;                               \
      *(ushort4*)&Bs[srow + j * 32][scol] = pb;                               \
    }                                                                         \
  }

  const int ks = (lane >> 4) * 8;
  const int fr = lane & 15;

  STAGE_LOAD(0);
  STAGE_WRITE();
  __syncthreads();

  for (int k0 = 0; k0 < HD; k0 += BKT) {
    const bool notlast = (k0 + BKT < HD);
    if (notlast) STAGE_LOAD(k0 + BKT);

    short8 af[4], bfv[4];
#pragma unroll
    for (int i = 0; i < 4; i++) {
      af[i] = *(const short8*)&As[wr * 64 + i * 16 + fr][ks];
      bfv[i] = *(const short8*)&Bs[wc * 64 + i * 16 + fr][ks];
    }
#pragma unroll
    for (int i = 0; i < 4; i++)
#pragma unroll
      for (int j = 0; j < 4; j++)
        acc[i][j] = __builtin_amdgcn_mfma_f32_16x16x32_bf16(af[i], bfv[j],
                                                            acc[i][j], 0, 0, 0);

    __syncthreads();
    if (notlast) STAGE_WRITE();
    __syncthreads();
  }
#undef STAGE_LOAD
#undef STAGE_WRITE

  float rsum[16];
#pragma unroll
  for (int mi = 0; mi < 4; mi++) {
#pragma unroll
    for (int r = 0; r < 4; r++) {
      float s = 0.f;
#pragma unroll
      for (int nj = 0; nj < 4; nj++) s += __expf(acc[mi][nj][r]);
      rsum[mi * 4 + r] = s;
    }
  }
#pragma unroll
  for (int m = 1; m < 16; m <<= 1) {
#pragma unroll
    for (int q = 0; q < 16; q++) rsum[q] += __shfl_xor(rsum[q], m, 64);
  }

  __syncthreads();
  float* red = (float*)&As[0][0];
  if (fr == 0) {
#pragma unroll
    for (int mi = 0; mi < 4; mi++)
#pragma unroll
      for (int r = 0; r < 4; r++)
        red[wave * 64 + mi * 16 + (lane >> 4) * 4 + r] = rsum[mi * 4 + r];
  }
  __syncthreads();

  if (t < BM) {
    int rl = t;
    int wrow = rl >> 6;
    float S = red[(wrow * 2 + 0) * 64 + (rl & 63)] +
              red[(wrow * 2 + 1) * 64 + (rl & 63)];
    partialS[(size_t)cb * BT + row0 + rl] = S;
  }

  const bool is64 = (*badcnt == 0);
#pragma unroll
  for (int mi = 0; mi < 4; mi++) {
#pragma unroll
    for (int r = 0; r < 4; r++) {
      int grow = row0 + wr * 64 + mi * 16 + ((lane >> 4) << 2) + r;
      long long tv = is64 ? ((const long long*)tgt)[grow]
                          : (long long)((const int*)tgt)[grow];
#pragma unroll
      for (int nj = 0; nj < 4; nj++) {
        int gcol = col0 + wc * 64 + nj * 16 + fr;
        if (tv == (long long)gcol) picked[grow] = acc[mi][nj][r];
      }
    }
  }
}

// ---------------------------------------------------------------------------
// Per-row: S = sum of ncb partials; nll = log(S) - picked.
// ---------------------------------------------------------------------------
__global__ void reduce_rows_kernel(const float* __restrict__ partialS,
                                   const float* __restrict__ picked,
                                   float* __restrict__ nll, int ncb) {
  int r = blockIdx.x * blockDim.x + threadIdx.x;
  if (r >= BT) return;
  float S = 0.f;
  for (int cb = 0; cb < ncb; cb++) S += partialS[(size_t)cb * BT + r];
  nll[r] = logf(fmaxf(S, 1e-37f)) - picked[r];
}

// ---------------------------------------------------------------------------
// Final: loss = sum(nll) / n_non_ignore
// ---------------------------------------------------------------------------
__global__ void reduce_final_kernel(const float* __restrict__ nll,
                                    const void* __restrict__ tgt,
                                    const int* __restrict__ badcnt,
                                    float* __restrict__ out) {
  __shared__ float ssum[256];
  __shared__ int scnt[256];
  int t = threadIdx.x;
  const bool is64 = (*badcnt == 0);
  float s = 0.f;
  int c = 0;
  for (int r = t; r < BT; r += 256) {
    s += nll[r];
    long long tv =
        is64 ? ((const long long*)tgt)[r] : (long long)((const int*)tgt)[r];
    c += (tv != (long long)IGNORE_IDX) ? 1 : 0;
  }
  ssum[t] = s;
  scnt[t] = c;
  __syncthreads();
  for (int o = 128; o > 0; o >>= 1) {
    if (t < o) {
      ssum[t] += ssum[t + o];
      scnt[t] += scnt[t + o];
    }
    __syncthreads();
  }
  if (t == 0) out[0] = ssum[0] / (float)scnt[0];
}

// ---------------------------------------------------------------------------
extern "C" void kernel_launch(void* const* d_in, const int* in_sizes, int n_in,
                              void* d_out, int out_size, void* d_ws,
                              size_t ws_size, hipStream_t stream) {
  const float* x = (const float*)d_in[0];
  const float* w = (const float*)d_in[1];
  const void* tgt = d_in[2];
  float* out = (float*)d_out;

  char* ws = (char*)d_ws;
  // ws layout:
  //   [0, offA)              : partialS (NCB*BT*4 = 4,096,000 B max)
  //   [offA, offA+16)        : badcnt flag (+pad)
  //   [offA+16, +BT*4)       : picked
  //   [.. +BT*4)             : nll
  //   [offX, +BT*HD*2)       : x as bf16
  //   [offW, +VD*HD*2)       : W as bf16
  const size_t offA = (size_t)NCB * BT * 4;
  float* partialS = (float*)ws;
  int* badcnt = (int*)(ws + offA);
  float* picked = (float*)(ws + offA + 16);
  float* nll = (float*)(ws + offA + 16 + (size_t)BT * 4);
  const size_t offX = offA + 16 + 2 * (size_t)BT * 4;
  const size_t offW = offX + (size_t)BT * HD * 2;
  const size_t need = offW + (size_t)VD * HD * 2;

  hipMemsetAsync(ws + offA, 0, 16 + (size_t)BT * 4, stream);

  detect_tgt_kernel<<<8, 256, 0, stream>>>((const long long*)tgt, badcnt);

  if (ws_size >= need) {
    unsigned short* xbf = (unsigned short*)(ws + offX);
    unsigned short* wbf = (unsigned short*)(ws + offW);
    cvt_bf16_kernel<<<2048, 256, 0, stream>>>(x, xbf, BT * HD / 8);
    cvt_bf16_kernel<<<2048, 256, 0, stream>>>(w, wbf, VD * HD / 8);
    gemm_lse_8ph_kernel<<<NRB2 * NCB2, 512, 0, stream>>>(xbf, wbf, tgt, badcnt,
                                                         partialS, picked);
    reduce_rows_kernel<<<BT / 256, 256, 0, stream>>>(partialS, picked, nll,
                                                     NCB2);
  } else {
    gemm_lse_kernel<<<NRB * NCB, 256, 0, stream>>>(x, w, tgt, badcnt, partialS,
                                                   picked);
    reduce_rows_kernel<<<BT / 256, 256, 0, stream>>>(partialS, picked, nll,
                                                     NCB);
  }

  reduce_final_kernel<<<1, 256, 0, stream>>>(nll, tgt, badcnt, out);
}